// Round 3
// baseline (3248.280 us; speedup 1.0000x reference)
//
#include <hip/hip_runtime.h>

#define NU 100000
#define NS 50000
#define NG 50
#define NW 20000
#define NT 10
#define CDIM 64
#define FDIM 384

// ---- dst-chunk bucketing (6 bucketed edge types; types 3,7 handled direct) --
#define CHUNK 128
#define CSHIFT 7
#define CMASK 127
#define NBINS 2503      // 391+782+391+391+157+391
#define PSTRIDE 800
#define BTOT 352

struct PrepArgs {
  const int* src[6];
  const int* dst[6];
  int E[6];
  int nchunk[6];
  int cbase[7];   // unified chunk-bin base per type
  int bbase[7];   // block range per type
  int* partial;   // [BTOT][PSTRIDE]
  int* chunktot;  // [NBINS]
  int* choff;     // [NBINS + 6] per-type offsets (base = cbase[t]+t)
  int* bucket[6]; // packed (src<<7)|dstLow per type
};

// Pass 1: per-block LDS histogram of dst>>7 (single pass, 3.2KB LDS).
__global__ __launch_bounds__(256) void hist_k(PrepArgs a) {
  __shared__ int bins[PSTRIDE];
  int b = blockIdx.x, t = threadIdx.x;
  int ty = 0;
  while (b >= a.bbase[ty + 1]) ++ty;
  int bl = b - a.bbase[ty], B = a.bbase[ty + 1] - a.bbase[ty];
  int n = a.nchunk[ty], E = a.E[ty];
  const int* __restrict__ dst = a.dst[ty];
  for (int i = t; i < n; i += 256) bins[i] = 0;
  __syncthreads();
  for (int i = bl * 256 + t; i < E; i += B * 256) atomicAdd(&bins[dst[i] >> CSHIFT], 1);
  __syncthreads();
  int* row = a.partial + (size_t)b * PSTRIDE;
  for (int i = t; i < n; i += 256) row[i] = bins[i];
}

// Column scan over blocks: partial -> exclusive per-block offsets; chunk totals.
__global__ __launch_bounds__(256) void scanb_k(PrepArgs a) {
  int bin = blockIdx.x * 256 + threadIdx.x;
  if (bin >= NBINS) return;
  int ty = 0;
  while (bin >= a.cbase[ty + 1]) ++ty;
  int l = bin - a.cbase[ty];
  int run = 0;
  for (int b = a.bbase[ty]; b < a.bbase[ty + 1]; ++b) {
    int* p = a.partial + (size_t)b * PSTRIDE + l;
    int v = *p;
    *p = run;
    run += v;
  }
  a.chunktot[bin] = run;
}

// Per-type exclusive scan of chunk totals (nchunk <= 782 < 1024).
__global__ __launch_bounds__(1024) void scanc_k(PrepArgs a) {
  __shared__ int sc[1024];
  int ty = blockIdx.x, t = threadIdx.x;
  int n = a.nchunk[ty];
  int v = (t < n) ? a.chunktot[a.cbase[ty] + t] : 0;
  sc[t] = v;
  __syncthreads();
  for (int d = 1; d < 1024; d <<= 1) {
    int u = (t >= d) ? sc[t - d] : 0;
    __syncthreads();
    sc[t] += u;
    __syncthreads();
  }
  int* choff = a.choff + a.cbase[ty] + ty;
  if (t < n) choff[t] = sc[t] - v;
  if (t == n - 1) choff[n] = sc[t];
}

// Pass 2: ranked fill of packed edges into chunk-grouped order.
__global__ __launch_bounds__(256) void fill_k(PrepArgs a) {
  __shared__ int bins[PSTRIDE];
  __shared__ int base[PSTRIDE];
  int b = blockIdx.x, t = threadIdx.x;
  int ty = 0;
  while (b >= a.bbase[ty + 1]) ++ty;
  int bl = b - a.bbase[ty], B = a.bbase[ty + 1] - a.bbase[ty];
  int n = a.nchunk[ty], E = a.E[ty];
  const int* __restrict__ dst = a.dst[ty];
  const int* __restrict__ src = a.src[ty];
  int* __restrict__ bucket = a.bucket[ty];
  const int* choff = a.choff + a.cbase[ty] + ty;
  const int* prow = a.partial + (size_t)b * PSTRIDE;
  for (int i = t; i < n; i += 256) { bins[i] = 0; base[i] = choff[i] + prow[i]; }
  __syncthreads();
  for (int i = bl * 256 + t; i < E; i += B * 256) {
    int d = dst[i];
    int l = d >> CSHIFT;
    int r = atomicAdd(&bins[l], 1);
    bucket[base[l] + r] = (src[i] << CSHIFT) | (d & CMASK);
  }
}

// ---------------------------------------------------------------------------
// Chunk-accumulate aggregation: one block per 128-dst chunk, 32KB LDS
// accumulator, conflict-free ds_add_f32, mean fused at writeout.
// ---------------------------------------------------------------------------
__global__ __launch_bounds__(256) void agg_chunk_k(const int* __restrict__ bucket,
                                                   const int* __restrict__ choff,
                                                   const float* __restrict__ x,
                                                   float* __restrict__ out, int nb) {
  __shared__ float acc[CHUNK * CDIM];
  __shared__ int cnt[CHUNK];
  int t = threadIdx.x, lane = t & 63, wv = t >> 6;
  for (int i = t; i < CHUNK * CDIM; i += 256) acc[i] = 0.f;
  for (int i = t; i < CHUNK; i += 256) cnt[i] = 0;
  __syncthreads();
  int c = blockIdx.x;
  int beg = choff[c], end = choff[c + 1];
  for (int j0 = beg + wv * 64; j0 < end; j0 += 256) {
    int myj = j0 + lane;
    int pk = (myj < end) ? bucket[myj] : 0;
    int m = min(64, end - j0);
    int j = 0;
    for (; j + 4 <= m; j += 4) {
      int p0 = __shfl(pk, j, 64), p1 = __shfl(pk, j + 1, 64);
      int p2 = __shfl(pk, j + 2, 64), p3 = __shfl(pk, j + 3, 64);
      float v0 = x[(size_t)(p0 >> CSHIFT) * CDIM + lane];
      float v1 = x[(size_t)(p1 >> CSHIFT) * CDIM + lane];
      float v2 = x[(size_t)(p2 >> CSHIFT) * CDIM + lane];
      float v3 = x[(size_t)(p3 >> CSHIFT) * CDIM + lane];
      atomicAdd(&acc[(p0 & CMASK) * CDIM + lane], v0);
      atomicAdd(&acc[(p1 & CMASK) * CDIM + lane], v1);
      atomicAdd(&acc[(p2 & CMASK) * CDIM + lane], v2);
      atomicAdd(&acc[(p3 & CMASK) * CDIM + lane], v3);
      if (lane == 0) {
        atomicAdd(&cnt[p0 & CMASK], 1); atomicAdd(&cnt[p1 & CMASK], 1);
        atomicAdd(&cnt[p2 & CMASK], 1); atomicAdd(&cnt[p3 & CMASK], 1);
      }
    }
    for (; j < m; ++j) {
      int p = __shfl(pk, j, 64);
      atomicAdd(&acc[(p & CMASK) * CDIM + lane], x[(size_t)(p >> CSHIFT) * CDIM + lane]);
      if (lane == 0) atomicAdd(&cnt[p & CMASK], 1);
    }
  }
  __syncthreads();
  int gbase = c * CHUNK;
  for (int r = wv; r < CHUNK; r += 4) {
    int gd = gbase + r;
    if (gd < nb) {
      int k = cnt[r];
      float s = acc[r * CDIM + lane];
      out[(size_t)gd * CDIM + lane] = (k > 0) ? s / (float)k : 0.f;
    }
  }
}

// Small-dst aggregation (genres=50, type=10): per-block LDS partials +
// coalesced global atomic merge.
__global__ __launch_bounds__(256) void agg_small_k(const int* __restrict__ src,
                                                   const int* __restrict__ dst, int E,
                                                   const float* __restrict__ x,
                                                   float* __restrict__ gacc,
                                                   int* __restrict__ gcnt, int nd, int G) {
  __shared__ float acc[NG * CDIM];
  __shared__ int cnt[NG];
  int t = threadIdx.x, lane = t & 63, wv = t >> 6;
  for (int i = t; i < nd * CDIM; i += 256) acc[i] = 0.f;
  for (int i = t; i < nd; i += 256) cnt[i] = 0;
  __syncthreads();
  for (int j0 = (blockIdx.x * 4 + wv) * 64; j0 < E; j0 += G * 256) {
    int myj = j0 + lane;
    int s = 0, d = 0;
    if (myj < E) { s = src[myj]; d = dst[myj]; }
    int m = min(64, E - j0);
    int j = 0;
    for (; j + 4 <= m; j += 4) {
      int s0 = __shfl(s, j, 64), s1 = __shfl(s, j + 1, 64);
      int s2 = __shfl(s, j + 2, 64), s3 = __shfl(s, j + 3, 64);
      int d0 = __shfl(d, j, 64), d1 = __shfl(d, j + 1, 64);
      int d2 = __shfl(d, j + 2, 64), d3 = __shfl(d, j + 3, 64);
      float v0 = x[(size_t)s0 * CDIM + lane];
      float v1 = x[(size_t)s1 * CDIM + lane];
      float v2 = x[(size_t)s2 * CDIM + lane];
      float v3 = x[(size_t)s3 * CDIM + lane];
      atomicAdd(&acc[d0 * CDIM + lane], v0);
      atomicAdd(&acc[d1 * CDIM + lane], v1);
      atomicAdd(&acc[d2 * CDIM + lane], v2);
      atomicAdd(&acc[d3 * CDIM + lane], v3);
      if (lane == 0) {
        atomicAdd(&cnt[d0], 1); atomicAdd(&cnt[d1], 1);
        atomicAdd(&cnt[d2], 1); atomicAdd(&cnt[d3], 1);
      }
    }
    for (; j < m; ++j) {
      int sj = __shfl(s, j, 64), dj = __shfl(d, j, 64);
      atomicAdd(&acc[dj * CDIM + lane], x[(size_t)sj * CDIM + lane]);
      if (lane == 0) atomicAdd(&cnt[dj], 1);
    }
  }
  __syncthreads();
  for (int r = wv; r < nd; r += 4) atomicAdd(&gacc[r * CDIM + lane], acc[r * CDIM + lane]);
  if (t < nd) atomicAdd(&gcnt[t], cnt[t]);
}

__global__ __launch_bounds__(256) void fin_small_k(float* __restrict__ gacc,
                                                   const int* __restrict__ gcnt, int nd) {
  int i = blockIdx.x * 256 + threadIdx.x;
  if (i < nd * CDIM) {
    int c = gcnt[i >> 6];
    gacc[i] = (c > 0) ? gacc[i] / (float)c : 0.f;
  }
}

// ---------------------------------------------------------------------------
// Segmented GEMM: out[m,c] = relu?( sum_seg sum_k A[m,k] * W[c,k] + bias )
// ---------------------------------------------------------------------------
struct GemmSeg { const float* A; const float* W; int F; };
struct GemmArgs {
  GemmSeg seg[8];
  const float* bias[4];
  float* out;
  int nseg, nbias, M, relu;
};

__global__ __launch_bounds__(256) void seg_gemm(GemmArgs args) {
  __shared__ __align__(16) float As[64][68];
  __shared__ __align__(16) float Bs[64][68];
  const int tid = threadIdx.x;
  const int tc = tid & 15;
  const int tm = tid >> 4;
  const int m0 = blockIdx.x * 64;
  const int lm = tid >> 4;
  const int lk = (tid & 15) * 4;

  float acc[4][4] = {};

  for (int s = 0; s < args.nseg; ++s) {
    const float* __restrict__ A = args.seg[s].A;
    const float* __restrict__ W = args.seg[s].W;
    const int F = args.seg[s].F;
    for (int k0 = 0; k0 < F; k0 += 64) {
#pragma unroll
      for (int i = 0; i < 4; ++i) {
        int m = i * 16 + lm;
        int gm = m0 + m;
        float4 v = make_float4(0.f, 0.f, 0.f, 0.f);
        if (gm < args.M) v = *(const float4*)(A + (size_t)gm * F + k0 + lk);
        As[lk + 0][m] = v.x; As[lk + 1][m] = v.y;
        As[lk + 2][m] = v.z; As[lk + 3][m] = v.w;
      }
#pragma unroll
      for (int i = 0; i < 4; ++i) {
        int c = i * 16 + lm;
        float4 v = *(const float4*)(W + (size_t)c * F + k0 + lk);
        Bs[lk + 0][c] = v.x; Bs[lk + 1][c] = v.y;
        Bs[lk + 2][c] = v.z; Bs[lk + 3][c] = v.w;
      }
      __syncthreads();
#pragma unroll 8
      for (int k = 0; k < 64; ++k) {
        float4 a = *(const float4*)&As[k][tm * 4];
        float4 w = *(const float4*)&Bs[k][tc * 4];
        acc[0][0] += a.x * w.x; acc[0][1] += a.x * w.y; acc[0][2] += a.x * w.z; acc[0][3] += a.x * w.w;
        acc[1][0] += a.y * w.x; acc[1][1] += a.y * w.y; acc[1][2] += a.y * w.z; acc[1][3] += a.y * w.w;
        acc[2][0] += a.z * w.x; acc[2][1] += a.z * w.y; acc[2][2] += a.z * w.z; acc[2][3] += a.z * w.w;
        acc[3][0] += a.w * w.x; acc[3][1] += a.w * w.y; acc[3][2] += a.w * w.z; acc[3][3] += a.w * w.w;
      }
      __syncthreads();
    }
  }

  float b[4] = {0.f, 0.f, 0.f, 0.f};
  for (int i = 0; i < args.nbias; ++i) {
    const float* bp = args.bias[i];
#pragma unroll
    for (int j = 0; j < 4; ++j) b[j] += bp[tc * 4 + j];
  }
#pragma unroll
  for (int i = 0; i < 4; ++i) {
    int gm = m0 + tm * 4 + i;
    if (gm < args.M) {
      float4 o;
      o.x = acc[i][0] + b[0];
      o.y = acc[i][1] + b[1];
      o.z = acc[i][2] + b[2];
      o.w = acc[i][3] + b[3];
      if (args.relu) {
        o.x = fmaxf(o.x, 0.f); o.y = fmaxf(o.y, 0.f);
        o.z = fmaxf(o.z, 0.f); o.w = fmaxf(o.w, 0.f);
      }
      *(float4*)(args.out + (size_t)gm * CDIM + tc * 4) = o;
    }
  }
}

// ---------------------------------------------------------------------------
// Edge scoring: one wave per edge, wave-reduce dot over 64 channels.
// ---------------------------------------------------------------------------
__global__ __launch_bounds__(256) void score_k(const int* __restrict__ eli, int E,
                                               const float* __restrict__ xu,
                                               const float* __restrict__ xs,
                                               float* __restrict__ out) {
  long long gid = (long long)blockIdx.x * 256 + threadIdx.x;
  int e = (int)(gid >> 6);
  int c = (int)(gid & 63);
  if (e < E) {
    int u = eli[e];
    int sv = eli[E + e];
    float p = xu[(size_t)u * CDIM + c] * xs[(size_t)sv * CDIM + c];
#pragma unroll
    for (int off = 32; off > 0; off >>= 1) p += __shfl_down(p, off, 64);
    if (c == 0) out[e] = p;
  }
}

extern "C" void kernel_launch(void* const* d_in, const int* in_sizes, int n_in,
                              void* d_out, int out_size, void* d_ws, size_t ws_size,
                              hipStream_t stream) {
  const float* reviews  = (const float*)d_in[0];
  const float* overview = (const float*)d_in[1];
  const float* g_emb    = (const float*)d_in[2];
  const float* w_emb    = (const float*)d_in[3];
  const float* t_emb    = (const float*)d_in[4];
  const float* Wu  = (const float*)d_in[5];
  const float* bu  = (const float*)d_in[6];
  const float* Wsp = (const float*)d_in[7];
  const float* bs  = (const float*)d_in[8];
  const float* Wl1 = (const float*)d_in[9];
  const float* bl1 = (const float*)d_in[10];
  const float* Wr1 = (const float*)d_in[11];
  const float* Wl2 = (const float*)d_in[12];
  const float* bl2 = (const float*)d_in[13];
  const float* Wr2 = (const float*)d_in[14];
  const int* e_u2s = (const int*)d_in[15];
  const int* e_g2s = (const int*)d_in[16];
  const int* e_w2s = (const int*)d_in[17];
  const int* e_t2s = (const int*)d_in[18];
  const int* eli   = (const int*)d_in[19];
  const int E_u = in_sizes[15] / 2;
  const int E_g = in_sizes[16] / 2;
  const int E_w = in_sizes[17] / 2;
  const int E_t = in_sizes[18] / 2;
  const int E_l = in_sizes[19] / 2;

  // ---- workspace layout (4B units) ----
  float* ws = (float*)d_ws;
  size_t off = 0;
  auto take = [&](size_t n) { float* p = ws + off; off += n; return p; };
  float* x0u = take((size_t)NU * CDIM);
  float* x0s = take((size_t)NS * CDIM);
  float* x1u = take((size_t)NU * CDIM);
  float* x1s = take((size_t)NS * CDIM);
  float* x1g = take((size_t)NG * CDIM);
  float* x1w = take((size_t)NW * CDIM);
  float* x1t = take((size_t)NT * CDIM);
  float* aggS0 = take((size_t)NS * CDIM);
  float* aggS2 = take((size_t)NS * CDIM);
  float* aggS4 = take((size_t)NS * CDIM);
  float* aggS6 = take((size_t)NS * CDIM);
  float* agg1  = aggS0;  // NU*CDIM alias over aggS0+aggS2 (disjoint lifetime)
  float* agg5  = take((size_t)NW * CDIM);
  // small-agg zero block: agg3, agg7, cnt3, cnt7 contiguous
  float* agg3  = take((size_t)NG * CDIM);
  float* agg7  = take((size_t)NT * CDIM);
  int* cnt3 = (int*)take(NG);
  int* cnt7 = (int*)take(NT);
  size_t zeroBytes = ((size_t)NG * CDIM + NT * CDIM + NG + NT) * 4;
  // buckets (types 0,1,2,4,5,6)
  int* bkt0 = (int*)take(E_u);
  int* bkt1 = (int*)take(E_u);
  int* bkt2 = (int*)take(E_g);
  int* bkt3 = (int*)take(E_w);   // edge type 4 (writer->series)
  int* bkt4 = (int*)take(E_w);   // edge type 5 (series->writer)
  int* bkt5 = (int*)take(E_t);   // edge type 6 (type->series)
  int* partial  = (int*)take((size_t)BTOT * PSTRIDE);
  int* chunktot = (int*)take(NBINS);
  int* choffG   = (int*)take(NBINS + 6);
  float* x2u = x0u;
  float* x2s = x0s;

  // ---- prep args ----
  PrepArgs pa{};
  // bucketed-type order: {t0 u->s, t1 s->u, t2 g->s, t4 w->s, t5 s->w, t6 t->s}
  const int* bsrc[6] = {e_u2s, e_u2s + E_u, e_g2s, e_w2s, e_w2s + E_w, e_t2s};
  const int* bdst[6] = {e_u2s + E_u, e_u2s, e_g2s + E_g, e_w2s + E_w, e_w2s, e_t2s + E_t};
  int bE[6]  = {E_u, E_u, E_g, E_w, E_w, E_t};
  int nch[6] = {391, 782, 391, 391, 157, 391};
  int cb[7]  = {0, 391, 1173, 1564, 1955, 2112, 2503};
  int bpt[6] = {128, 128, 32, 16, 16, 32};
  int* bkts[6] = {bkt0, bkt1, bkt2, bkt3, bkt4, bkt5};
  int bb = 0;
  for (int i = 0; i < 6; ++i) {
    pa.src[i] = bsrc[i]; pa.dst[i] = bdst[i]; pa.E[i] = bE[i];
    pa.nchunk[i] = nch[i]; pa.cbase[i] = cb[i];
    pa.bbase[i] = bb; bb += bpt[i];
    pa.bucket[i] = bkts[i];
  }
  pa.cbase[6] = cb[6]; pa.bbase[6] = bb;
  pa.partial = partial; pa.chunktot = chunktot; pa.choff = choffG;
  const int* choffT[6];
  for (int i = 0; i < 6; ++i) choffT[i] = choffG + cb[i] + i;
  int nbT[6] = {NS, NU, NS, NS, NW, NS};

  // ---- prep (4 dispatches, no global atomics) ----
  hist_k<<<BTOT, 256, 0, stream>>>(pa);
  scanb_k<<<(NBINS + 255) / 256, 256, 0, stream>>>(pa);
  scanc_k<<<6, 1024, 0, stream>>>(pa);
  fill_k<<<BTOT, 256, 0, stream>>>(pa);
  hipMemsetAsync(agg3, 0, zeroBytes, stream);

  // aggs that need only prep (+const embeddings)
  agg_chunk_k<<<nch[2], 256, 0, stream>>>(bkt2, choffT[2], g_emb, aggS2, nbT[2]);
  agg_chunk_k<<<nch[3], 256, 0, stream>>>(bkt3, choffT[3], w_emb, aggS4, nbT[3]);
  agg_chunk_k<<<nch[5], 256, 0, stream>>>(bkt5, choffT[5], t_emb, aggS6, nbT[5]);

  // ---- projections ----
  {
    GemmArgs a{};
    a.seg[0] = {reviews, Wu, FDIM}; a.nseg = 1;
    a.bias[0] = bu; a.nbias = 1;
    a.out = x0u; a.M = NU; a.relu = 0;
    seg_gemm<<<(NU + 63) / 64, 256, 0, stream>>>(a);
  }
  {
    GemmArgs a{};
    a.seg[0] = {overview, Wsp, FDIM}; a.nseg = 1;
    a.bias[0] = bs; a.nbias = 1;
    a.out = x0s; a.M = NS; a.relu = 0;
    seg_gemm<<<(NS + 63) / 64, 256, 0, stream>>>(a);
  }

  // ---- layer 1 ----
  agg_chunk_k<<<nch[0], 256, 0, stream>>>(bkt0, choffT[0], x0u, aggS0, nbT[0]);
  {  // series
    GemmArgs a{};
    a.seg[0] = {aggS0, Wl1 + 0 * 4096, 64};
    a.seg[1] = {aggS2, Wl1 + 2 * 4096, 64};
    a.seg[2] = {aggS4, Wl1 + 4 * 4096, 64};
    a.seg[3] = {aggS6, Wl1 + 6 * 4096, 64};
    a.seg[4] = {x0s, Wr1 + 0 * 4096, 64};
    a.seg[5] = {x0s, Wr1 + 2 * 4096, 64};
    a.seg[6] = {x0s, Wr1 + 4 * 4096, 64};
    a.seg[7] = {x0s, Wr1 + 6 * 4096, 64};
    a.nseg = 8;
    a.bias[0] = bl1 + 0 * 64; a.bias[1] = bl1 + 2 * 64;
    a.bias[2] = bl1 + 4 * 64; a.bias[3] = bl1 + 6 * 64; a.nbias = 4;
    a.out = x1s; a.M = NS; a.relu = 1;
    seg_gemm<<<(NS + 63) / 64, 256, 0, stream>>>(a);
  }
  // users (agg1 aliases aggS0/aggS2 -- series GEMM already consumed them)
  agg_chunk_k<<<nch[1], 256, 0, stream>>>(bkt1, choffT[1], x0s, agg1, nbT[1]);
  {
    GemmArgs a{};
    a.seg[0] = {agg1, Wl1 + 1 * 4096, 64};
    a.seg[1] = {x0u, Wr1 + 1 * 4096, 64};
    a.nseg = 2;
    a.bias[0] = bl1 + 1 * 64; a.nbias = 1;
    a.out = x1u; a.M = NU; a.relu = 1;
    seg_gemm<<<(NU + 63) / 64, 256, 0, stream>>>(a);
  }
  // genres (direct small)
  agg_small_k<<<128, 256, 0, stream>>>(e_g2s + E_g, e_g2s, E_g, x0s, agg3, cnt3, NG, 128);
  fin_small_k<<<(NG * CDIM + 255) / 256, 256, 0, stream>>>(agg3, cnt3, NG);
  {
    GemmArgs a{};
    a.seg[0] = {agg3, Wl1 + 3 * 4096, 64};
    a.seg[1] = {g_emb, Wr1 + 3 * 4096, 64};
    a.nseg = 2;
    a.bias[0] = bl1 + 3 * 64; a.nbias = 1;
    a.out = x1g; a.M = NG; a.relu = 1;
    seg_gemm<<<(NG + 63) / 64, 256, 0, stream>>>(a);
  }
  // writer (chunked, edge type 5 = bt 4)
  agg_chunk_k<<<nch[4], 256, 0, stream>>>(bkt4, choffT[4], x0s, agg5, nbT[4]);
  {
    GemmArgs a{};
    a.seg[0] = {agg5, Wl1 + 5 * 4096, 64};
    a.seg[1] = {w_emb, Wr1 + 5 * 4096, 64};
    a.nseg = 2;
    a.bias[0] = bl1 + 5 * 64; a.nbias = 1;
    a.out = x1w; a.M = NW; a.relu = 1;
    seg_gemm<<<(NW + 63) / 64, 256, 0, stream>>>(a);
  }
  // type (direct small)
  agg_small_k<<<64, 256, 0, stream>>>(e_t2s + E_t, e_t2s, E_t, x0s, agg7, cnt7, NT, 64);
  fin_small_k<<<(NT * CDIM + 255) / 256, 256, 0, stream>>>(agg7, cnt7, NT);
  {
    GemmArgs a{};
    a.seg[0] = {agg7, Wl1 + 7 * 4096, 64};
    a.seg[1] = {t_emb, Wr1 + 7 * 4096, 64};
    a.nseg = 2;
    a.bias[0] = bl1 + 7 * 64; a.nbias = 1;
    a.out = x1t; a.M = NT; a.relu = 1;
    seg_gemm<<<(NT + 63) / 64, 256, 0, stream>>>(a);
  }

  // ---- layer 2 ----
  agg_chunk_k<<<nch[0], 256, 0, stream>>>(bkt0, choffT[0], x1u, aggS0, nbT[0]);
  agg_chunk_k<<<nch[2], 256, 0, stream>>>(bkt2, choffT[2], x1g, aggS2, nbT[2]);
  agg_chunk_k<<<nch[3], 256, 0, stream>>>(bkt3, choffT[3], x1w, aggS4, nbT[3]);
  agg_chunk_k<<<nch[5], 256, 0, stream>>>(bkt5, choffT[5], x1t, aggS6, nbT[5]);
  {  // series -> x2s
    GemmArgs a{};
    a.seg[0] = {aggS0, Wl2 + 0 * 4096, 64};
    a.seg[1] = {aggS2, Wl2 + 2 * 4096, 64};
    a.seg[2] = {aggS4, Wl2 + 4 * 4096, 64};
    a.seg[3] = {aggS6, Wl2 + 6 * 4096, 64};
    a.seg[4] = {x1s, Wr2 + 0 * 4096, 64};
    a.seg[5] = {x1s, Wr2 + 2 * 4096, 64};
    a.seg[6] = {x1s, Wr2 + 4 * 4096, 64};
    a.seg[7] = {x1s, Wr2 + 6 * 4096, 64};
    a.nseg = 8;
    a.bias[0] = bl2 + 0 * 64; a.bias[1] = bl2 + 2 * 64;
    a.bias[2] = bl2 + 4 * 64; a.bias[3] = bl2 + 6 * 64; a.nbias = 4;
    a.out = x2s; a.M = NS; a.relu = 0;
    seg_gemm<<<(NS + 63) / 64, 256, 0, stream>>>(a);
  }
  agg_chunk_k<<<nch[1], 256, 0, stream>>>(bkt1, choffT[1], x1s, agg1, nbT[1]);
  {  // users -> x2u
    GemmArgs a{};
    a.seg[0] = {agg1, Wl2 + 1 * 4096, 64};
    a.seg[1] = {x1u, Wr2 + 1 * 4096, 64};
    a.nseg = 2;
    a.bias[0] = bl2 + 1 * 64; a.nbias = 1;
    a.out = x2u; a.M = NU; a.relu = 0;
    seg_gemm<<<(NU + 63) / 64, 256, 0, stream>>>(a);
  }

  // ---- scoring ----
  score_k<<<((long long)E_l * 64 + 255) / 256, 256, 0, stream>>>(
      eli, E_l, x2u, x2s, (float*)d_out);
}

// Round 4
// 1340.178 us; speedup vs baseline: 2.4238x; 2.4238x over previous
//
#include <hip/hip_runtime.h>

#define NU 100000
#define NS 50000
#define NG 50
#define NW 20000
#define NT 10
#define CDIM 64
#define FDIM 384

// ---- dst-chunk bucketing (6 bucketed edge types; types 3,7 handled direct) --
#define CHUNK 128
#define CSHIFT 7
#define CMASK 127
#define NBINS 2503      // 391+782+391+391+157+391
#define PSTRIDE 800
#define BTOT 352
#define CTOT 2503       // total chunks (csr_k grid)

struct PrepArgs {
  const int* src[6];
  const int* dst[6];
  int E[6];
  int nchunk[6];
  int nb[6];
  int cbase[7];   // unified chunk-bin base per type
  int bbase[7];   // hist/fill block range per type
  int cstart[7];  // csr_k block range per type (prefix of nchunk)
  int* partial;   // [BTOT][PSTRIDE]
  int* chunktot;  // [NBINS]
  int* choff;     // [NBINS + 6] per-type chunk offsets (base = cbase[t]+t)
  int* bucket[6]; // packed (src<<7)|dstLow per type
  int* adj[6];    // CSR adjacency (src ids, dst-sorted)
  int* off[6];    // CSR offsets per type (nb+1)
};

// Pass 1: per-block LDS histogram of dst>>7 (single pass, 3.2KB LDS).
__global__ __launch_bounds__(256) void hist_k(PrepArgs a) {
  __shared__ int bins[PSTRIDE];
  int b = blockIdx.x, t = threadIdx.x;
  int ty = 0;
  while (b >= a.bbase[ty + 1]) ++ty;
  int bl = b - a.bbase[ty], B = a.bbase[ty + 1] - a.bbase[ty];
  int n = a.nchunk[ty], E = a.E[ty];
  const int* __restrict__ dst = a.dst[ty];
  for (int i = t; i < n; i += 256) bins[i] = 0;
  __syncthreads();
  for (int i = bl * 256 + t; i < E; i += B * 256) atomicAdd(&bins[dst[i] >> CSHIFT], 1);
  __syncthreads();
  int* row = a.partial + (size_t)b * PSTRIDE;
  for (int i = t; i < n; i += 256) row[i] = bins[i];
}

// Column scan over blocks: partial -> exclusive per-block offsets; chunk totals.
__global__ __launch_bounds__(256) void scanb_k(PrepArgs a) {
  int bin = blockIdx.x * 256 + threadIdx.x;
  if (bin >= NBINS) return;
  int ty = 0;
  while (bin >= a.cbase[ty + 1]) ++ty;
  int l = bin - a.cbase[ty];
  int run = 0;
  for (int b = a.bbase[ty]; b < a.bbase[ty + 1]; ++b) {
    int* p = a.partial + (size_t)b * PSTRIDE + l;
    int v = *p;
    *p = run;
    run += v;
  }
  a.chunktot[bin] = run;
}

// Per-type exclusive scan of chunk totals (nchunk <= 782 < 1024).
__global__ __launch_bounds__(1024) void scanc_k(PrepArgs a) {
  __shared__ int sc[1024];
  int ty = blockIdx.x, t = threadIdx.x;
  int n = a.nchunk[ty];
  int v = (t < n) ? a.chunktot[a.cbase[ty] + t] : 0;
  sc[t] = v;
  __syncthreads();
  for (int d = 1; d < 1024; d <<= 1) {
    int u = (t >= d) ? sc[t - d] : 0;
    __syncthreads();
    sc[t] += u;
    __syncthreads();
  }
  int* choff = a.choff + a.cbase[ty] + ty;
  if (t < n) choff[t] = sc[t] - v;
  if (t == n - 1) choff[n] = sc[t];
}

// Pass 2: ranked fill of packed edges into chunk-grouped order.
__global__ __launch_bounds__(256) void fill_k(PrepArgs a) {
  __shared__ int bins[PSTRIDE];
  __shared__ int base[PSTRIDE];
  int b = blockIdx.x, t = threadIdx.x;
  int ty = 0;
  while (b >= a.bbase[ty + 1]) ++ty;
  int bl = b - a.bbase[ty], B = a.bbase[ty + 1] - a.bbase[ty];
  int n = a.nchunk[ty], E = a.E[ty];
  const int* __restrict__ dst = a.dst[ty];
  const int* __restrict__ src = a.src[ty];
  int* __restrict__ bucket = a.bucket[ty];
  const int* choff = a.choff + a.cbase[ty] + ty;
  const int* prow = a.partial + (size_t)b * PSTRIDE;
  for (int i = t; i < n; i += 256) { bins[i] = 0; base[i] = choff[i] + prow[i]; }
  __syncthreads();
  for (int i = bl * 256 + t; i < E; i += B * 256) {
    int d = dst[i];
    int l = d >> CSHIFT;
    int r = atomicAdd(&bins[l], 1);
    bucket[base[l] + r] = (src[i] << CSHIFT) | (d & CMASK);
  }
}

// Pass 3: per-chunk counting sort by dstLow -> exact CSR (adj + off).
// One block per chunk; two strided passes over the chunk's bucket segment.
__global__ __launch_bounds__(256) void csr_k(PrepArgs a) {
  __shared__ int bins[CHUNK];
  __shared__ int sc[CHUNK];
  __shared__ int basea[CHUNK];
  int b = blockIdx.x, t = threadIdx.x;
  int ty = 0;
  while (b >= a.cstart[ty + 1]) ++ty;
  int c = b - a.cstart[ty];
  const int* __restrict__ bucket = a.bucket[ty];
  const int* choff = a.choff + a.cbase[ty] + ty;
  int beg = choff[c], end = choff[c + 1];
  if (t < CHUNK) bins[t] = 0;
  __syncthreads();
  for (int i = beg + t; i < end; i += 256) atomicAdd(&bins[bucket[i] & CMASK], 1);
  __syncthreads();
  int v = (t < CHUNK) ? bins[t] : 0;
  if (t < CHUNK) sc[t] = v;
  __syncthreads();
#pragma unroll
  for (int d = 1; d < CHUNK; d <<= 1) {
    int u = (t < CHUNK && t >= d) ? sc[t - d] : 0;
    __syncthreads();
    if (t < CHUNK) sc[t] += u;
    __syncthreads();
  }
  if (t < CHUNK) { basea[t] = beg + sc[t] - v; bins[t] = basea[t]; }
  __syncthreads();
  int gbase = c * CHUNK;
  int nb = a.nb[ty];
  if (t < CHUNK && gbase + t < nb) a.off[ty][gbase + t] = basea[t];
  if (b == a.cstart[ty + 1] - 1 && t == 0) a.off[ty][nb] = choff[a.nchunk[ty]];
  int* __restrict__ adj = a.adj[ty];
  for (int i = beg + t; i < end; i += 256) {
    int pk = bucket[i];
    int r = atomicAdd(&bins[pk & CMASK], 1);
    adj[r] = pk >> CSHIFT;
  }
}

// ---------------------------------------------------------------------------
// CSR gather aggregation (mean fused): one wave per dst node, lane = channel.
// adj loads are wave-uniform (HW broadcast); row loads coalesced 256B; all
// loads independent across the unroll -> deep MLP, no DS ops in the loop.
// ---------------------------------------------------------------------------
__global__ __launch_bounds__(256) void agg_csr_k(const int* __restrict__ adj,
                                                 const int* __restrict__ off,
                                                 const float* __restrict__ x,
                                                 float* __restrict__ out, int N) {
  int wid = (blockIdx.x * 256 + threadIdx.x) >> 6;
  int lane = threadIdx.x & 63;
  if (wid >= N) return;
  int beg = off[wid], deg = off[wid + 1] - beg;
  float a0 = 0.f, a1 = 0.f, a2 = 0.f, a3 = 0.f;
  int j = 0;
  for (; j + 4 <= deg; j += 4) {
    int s0 = adj[beg + j], s1 = adj[beg + j + 1];
    int s2 = adj[beg + j + 2], s3 = adj[beg + j + 3];
    a0 += x[(size_t)s0 * CDIM + lane];
    a1 += x[(size_t)s1 * CDIM + lane];
    a2 += x[(size_t)s2 * CDIM + lane];
    a3 += x[(size_t)s3 * CDIM + lane];
  }
  for (; j < deg; ++j) a0 += x[(size_t)adj[beg + j] * CDIM + lane];
  float s = (a0 + a1) + (a2 + a3);
  out[(size_t)wid * CDIM + lane] = (deg > 0) ? s / (float)deg : 0.f;
}

// Small-dst aggregation (genres=50, type=10): per-block LDS partials +
// coalesced global atomic merge.
__global__ __launch_bounds__(256) void agg_small_k(const int* __restrict__ src,
                                                   const int* __restrict__ dst, int E,
                                                   const float* __restrict__ x,
                                                   float* __restrict__ gacc,
                                                   int* __restrict__ gcnt, int nd, int G) {
  __shared__ float acc[NG * CDIM];
  __shared__ int cnt[NG];
  int t = threadIdx.x, lane = t & 63, wv = t >> 6;
  for (int i = t; i < nd * CDIM; i += 256) acc[i] = 0.f;
  for (int i = t; i < nd; i += 256) cnt[i] = 0;
  __syncthreads();
  for (int j0 = (blockIdx.x * 4 + wv) * 64; j0 < E; j0 += G * 256) {
    int myj = j0 + lane;
    int s = 0, d = 0;
    if (myj < E) { s = src[myj]; d = dst[myj]; }
    int m = min(64, E - j0);
    int j = 0;
    for (; j + 4 <= m; j += 4) {
      int s0 = __shfl(s, j, 64), s1 = __shfl(s, j + 1, 64);
      int s2 = __shfl(s, j + 2, 64), s3 = __shfl(s, j + 3, 64);
      int d0 = __shfl(d, j, 64), d1 = __shfl(d, j + 1, 64);
      int d2 = __shfl(d, j + 2, 64), d3 = __shfl(d, j + 3, 64);
      float v0 = x[(size_t)s0 * CDIM + lane];
      float v1 = x[(size_t)s1 * CDIM + lane];
      float v2 = x[(size_t)s2 * CDIM + lane];
      float v3 = x[(size_t)s3 * CDIM + lane];
      atomicAdd(&acc[d0 * CDIM + lane], v0);
      atomicAdd(&acc[d1 * CDIM + lane], v1);
      atomicAdd(&acc[d2 * CDIM + lane], v2);
      atomicAdd(&acc[d3 * CDIM + lane], v3);
      if (lane == 0) {
        atomicAdd(&cnt[d0], 1); atomicAdd(&cnt[d1], 1);
        atomicAdd(&cnt[d2], 1); atomicAdd(&cnt[d3], 1);
      }
    }
    for (; j < m; ++j) {
      int sj = __shfl(s, j, 64), dj = __shfl(d, j, 64);
      atomicAdd(&acc[dj * CDIM + lane], x[(size_t)sj * CDIM + lane]);
      if (lane == 0) atomicAdd(&cnt[dj], 1);
    }
  }
  __syncthreads();
  for (int r = wv; r < nd; r += 4) atomicAdd(&gacc[r * CDIM + lane], acc[r * CDIM + lane]);
  if (t < nd) atomicAdd(&gcnt[t], cnt[t]);
}

__global__ __launch_bounds__(256) void fin_small_k(float* __restrict__ gacc,
                                                   const int* __restrict__ gcnt, int nd) {
  int i = blockIdx.x * 256 + threadIdx.x;
  if (i < nd * CDIM) {
    int c = gcnt[i >> 6];
    gacc[i] = (c > 0) ? gacc[i] / (float)c : 0.f;
  }
}

// ---------------------------------------------------------------------------
// Segmented GEMM: out[m,c] = relu?( sum_seg sum_k A[m,k] * W[c,k] + bias )
// ---------------------------------------------------------------------------
struct GemmSeg { const float* A; const float* W; int F; };
struct GemmArgs {
  GemmSeg seg[8];
  const float* bias[4];
  float* out;
  int nseg, nbias, M, relu;
};

__global__ __launch_bounds__(256) void seg_gemm(GemmArgs args) {
  __shared__ __align__(16) float As[64][68];
  __shared__ __align__(16) float Bs[64][68];
  const int tid = threadIdx.x;
  const int tc = tid & 15;
  const int tm = tid >> 4;
  const int m0 = blockIdx.x * 64;
  const int lm = tid >> 4;
  const int lk = (tid & 15) * 4;

  float acc[4][4] = {};

  for (int s = 0; s < args.nseg; ++s) {
    const float* __restrict__ A = args.seg[s].A;
    const float* __restrict__ W = args.seg[s].W;
    const int F = args.seg[s].F;
    for (int k0 = 0; k0 < F; k0 += 64) {
#pragma unroll
      for (int i = 0; i < 4; ++i) {
        int m = i * 16 + lm;
        int gm = m0 + m;
        float4 v = make_float4(0.f, 0.f, 0.f, 0.f);
        if (gm < args.M) v = *(const float4*)(A + (size_t)gm * F + k0 + lk);
        As[lk + 0][m] = v.x; As[lk + 1][m] = v.y;
        As[lk + 2][m] = v.z; As[lk + 3][m] = v.w;
      }
#pragma unroll
      for (int i = 0; i < 4; ++i) {
        int c = i * 16 + lm;
        float4 v = *(const float4*)(W + (size_t)c * F + k0 + lk);
        Bs[lk + 0][c] = v.x; Bs[lk + 1][c] = v.y;
        Bs[lk + 2][c] = v.z; Bs[lk + 3][c] = v.w;
      }
      __syncthreads();
#pragma unroll 8
      for (int k = 0; k < 64; ++k) {
        float4 a = *(const float4*)&As[k][tm * 4];
        float4 w = *(const float4*)&Bs[k][tc * 4];
        acc[0][0] += a.x * w.x; acc[0][1] += a.x * w.y; acc[0][2] += a.x * w.z; acc[0][3] += a.x * w.w;
        acc[1][0] += a.y * w.x; acc[1][1] += a.y * w.y; acc[1][2] += a.y * w.z; acc[1][3] += a.y * w.w;
        acc[2][0] += a.z * w.x; acc[2][1] += a.z * w.y; acc[2][2] += a.z * w.z; acc[2][3] += a.z * w.w;
        acc[3][0] += a.w * w.x; acc[3][1] += a.w * w.y; acc[3][2] += a.w * w.z; acc[3][3] += a.w * w.w;
      }
      __syncthreads();
    }
  }

  float b[4] = {0.f, 0.f, 0.f, 0.f};
  for (int i = 0; i < args.nbias; ++i) {
    const float* bp = args.bias[i];
#pragma unroll
    for (int j = 0; j < 4; ++j) b[j] += bp[tc * 4 + j];
  }
#pragma unroll
  for (int i = 0; i < 4; ++i) {
    int gm = m0 + tm * 4 + i;
    if (gm < args.M) {
      float4 o;
      o.x = acc[i][0] + b[0];
      o.y = acc[i][1] + b[1];
      o.z = acc[i][2] + b[2];
      o.w = acc[i][3] + b[3];
      if (args.relu) {
        o.x = fmaxf(o.x, 0.f); o.y = fmaxf(o.y, 0.f);
        o.z = fmaxf(o.z, 0.f); o.w = fmaxf(o.w, 0.f);
      }
      *(float4*)(args.out + (size_t)gm * CDIM + tc * 4) = o;
    }
  }
}

// ---------------------------------------------------------------------------
// Edge scoring: one wave per edge, wave-reduce dot over 64 channels.
// ---------------------------------------------------------------------------
__global__ __launch_bounds__(256) void score_k(const int* __restrict__ eli, int E,
                                               const float* __restrict__ xu,
                                               const float* __restrict__ xs,
                                               float* __restrict__ out) {
  long long gid = (long long)blockIdx.x * 256 + threadIdx.x;
  int e = (int)(gid >> 6);
  int c = (int)(gid & 63);
  if (e < E) {
    int u = eli[e];
    int sv = eli[E + e];
    float p = xu[(size_t)u * CDIM + c] * xs[(size_t)sv * CDIM + c];
#pragma unroll
    for (int off = 32; off > 0; off >>= 1) p += __shfl_down(p, off, 64);
    if (c == 0) out[e] = p;
  }
}

extern "C" void kernel_launch(void* const* d_in, const int* in_sizes, int n_in,
                              void* d_out, int out_size, void* d_ws, size_t ws_size,
                              hipStream_t stream) {
  const float* reviews  = (const float*)d_in[0];
  const float* overview = (const float*)d_in[1];
  const float* g_emb    = (const float*)d_in[2];
  const float* w_emb    = (const float*)d_in[3];
  const float* t_emb    = (const float*)d_in[4];
  const float* Wu  = (const float*)d_in[5];
  const float* bu  = (const float*)d_in[6];
  const float* Wsp = (const float*)d_in[7];
  const float* bs  = (const float*)d_in[8];
  const float* Wl1 = (const float*)d_in[9];
  const float* bl1 = (const float*)d_in[10];
  const float* Wr1 = (const float*)d_in[11];
  const float* Wl2 = (const float*)d_in[12];
  const float* bl2 = (const float*)d_in[13];
  const float* Wr2 = (const float*)d_in[14];
  const int* e_u2s = (const int*)d_in[15];
  const int* e_g2s = (const int*)d_in[16];
  const int* e_w2s = (const int*)d_in[17];
  const int* e_t2s = (const int*)d_in[18];
  const int* eli   = (const int*)d_in[19];
  const int E_u = in_sizes[15] / 2;
  const int E_g = in_sizes[16] / 2;
  const int E_w = in_sizes[17] / 2;
  const int E_t = in_sizes[18] / 2;
  const int E_l = in_sizes[19] / 2;

  // ---- workspace layout (4B units) ----
  float* ws = (float*)d_ws;
  size_t off = 0;
  auto take = [&](size_t n) { float* p = ws + off; off += n; return p; };
  float* x0u = take((size_t)NU * CDIM);
  float* x0s = take((size_t)NS * CDIM);
  float* x1u = take((size_t)NU * CDIM);
  float* x1s = take((size_t)NS * CDIM);
  float* x1g = take((size_t)NG * CDIM);
  float* x1w = take((size_t)NW * CDIM);
  float* x1t = take((size_t)NT * CDIM);
  float* aggS0 = take((size_t)NS * CDIM);
  float* aggS2 = take((size_t)NS * CDIM);
  float* aggS4 = take((size_t)NS * CDIM);
  float* aggS6 = take((size_t)NS * CDIM);
  float* agg1  = aggS0;  // NU*CDIM alias over aggS0+aggS2 (disjoint lifetime)
  float* agg5  = take((size_t)NW * CDIM);
  // small-agg zero block: agg3, agg7, cnt3, cnt7 contiguous
  float* agg3  = take((size_t)NG * CDIM);
  float* agg7  = take((size_t)NT * CDIM);
  int* cnt3 = (int*)take(NG);
  int* cnt7 = (int*)take(NT);
  size_t zeroBytes = ((size_t)NG * CDIM + NT * CDIM + NG + NT) * 4;
  // buckets + CSR (types 0,1,2,4,5,6)
  int* bkt0 = (int*)take(E_u);
  int* bkt1 = (int*)take(E_u);
  int* bkt2 = (int*)take(E_g);
  int* bkt3 = (int*)take(E_w);   // edge type 4 (writer->series)
  int* bkt4 = (int*)take(E_w);   // edge type 5 (series->writer)
  int* bkt5 = (int*)take(E_t);   // edge type 6 (type->series)
  int* adj0 = (int*)take(E_u);
  int* adj1 = (int*)take(E_u);
  int* adj2 = (int*)take(E_g);
  int* adj3 = (int*)take(E_w);
  int* adj4 = (int*)take(E_w);
  int* adj5 = (int*)take(E_t);
  int* off0 = (int*)take(NS + 1);
  int* off1 = (int*)take(NU + 1);
  int* off2 = (int*)take(NS + 1);
  int* off3 = (int*)take(NS + 1);
  int* off4 = (int*)take(NW + 1);
  int* off5 = (int*)take(NS + 1);
  int* partial  = (int*)take((size_t)BTOT * PSTRIDE);
  int* chunktot = (int*)take(NBINS);
  int* choffG   = (int*)take(NBINS + 6);
  float* x2u = x0u;
  float* x2s = x0s;

  // ---- prep args ----
  PrepArgs pa{};
  // bucketed-type order: {t0 u->s, t1 s->u, t2 g->s, t4 w->s, t5 s->w, t6 t->s}
  const int* bsrc[6] = {e_u2s, e_u2s + E_u, e_g2s, e_w2s, e_w2s + E_w, e_t2s};
  const int* bdst[6] = {e_u2s + E_u, e_u2s, e_g2s + E_g, e_w2s + E_w, e_w2s, e_t2s + E_t};
  int bE[6]  = {E_u, E_u, E_g, E_w, E_w, E_t};
  int nch[6] = {391, 782, 391, 391, 157, 391};
  int cb[7]  = {0, 391, 1173, 1564, 1955, 2112, 2503};
  int bpt[6] = {128, 128, 32, 16, 16, 32};
  int nbT[6] = {NS, NU, NS, NS, NW, NS};
  int* bkts[6] = {bkt0, bkt1, bkt2, bkt3, bkt4, bkt5};
  int* adjs[6] = {adj0, adj1, adj2, adj3, adj4, adj5};
  int* offs[6] = {off0, off1, off2, off3, off4, off5};
  int bb = 0, cs = 0;
  for (int i = 0; i < 6; ++i) {
    pa.src[i] = bsrc[i]; pa.dst[i] = bdst[i]; pa.E[i] = bE[i];
    pa.nchunk[i] = nch[i]; pa.nb[i] = nbT[i]; pa.cbase[i] = cb[i];
    pa.bbase[i] = bb; bb += bpt[i];
    pa.cstart[i] = cs; cs += nch[i];
    pa.bucket[i] = bkts[i]; pa.adj[i] = adjs[i]; pa.off[i] = offs[i];
  }
  pa.cbase[6] = cb[6]; pa.bbase[6] = bb; pa.cstart[6] = cs;
  pa.partial = partial; pa.chunktot = chunktot; pa.choff = choffG;

  // ---- prep (5 dispatches, no global atomics) ----
  hist_k<<<BTOT, 256, 0, stream>>>(pa);
  scanb_k<<<(NBINS + 255) / 256, 256, 0, stream>>>(pa);
  scanc_k<<<6, 1024, 0, stream>>>(pa);
  fill_k<<<BTOT, 256, 0, stream>>>(pa);
  csr_k<<<CTOT, 256, 0, stream>>>(pa);
  hipMemsetAsync(agg3, 0, zeroBytes, stream);

  // aggs that need only prep (+const embeddings)
  agg_csr_k<<<(NS * 64 + 255) / 256, 256, 0, stream>>>(adj2, off2, g_emb, aggS2, NS);
  agg_csr_k<<<(NS * 64 + 255) / 256, 256, 0, stream>>>(adj3, off3, w_emb, aggS4, NS);
  agg_csr_k<<<(NS * 64 + 255) / 256, 256, 0, stream>>>(adj5, off5, t_emb, aggS6, NS);

  // ---- projections ----
  {
    GemmArgs a{};
    a.seg[0] = {reviews, Wu, FDIM}; a.nseg = 1;
    a.bias[0] = bu; a.nbias = 1;
    a.out = x0u; a.M = NU; a.relu = 0;
    seg_gemm<<<(NU + 63) / 64, 256, 0, stream>>>(a);
  }
  {
    GemmArgs a{};
    a.seg[0] = {overview, Wsp, FDIM}; a.nseg = 1;
    a.bias[0] = bs; a.nbias = 1;
    a.out = x0s; a.M = NS; a.relu = 0;
    seg_gemm<<<(NS + 63) / 64, 256, 0, stream>>>(a);
  }

  // ---- layer 1 ----
  agg_csr_k<<<(NS * 64 + 255) / 256, 256, 0, stream>>>(adj0, off0, x0u, aggS0, NS);
  {  // series
    GemmArgs a{};
    a.seg[0] = {aggS0, Wl1 + 0 * 4096, 64};
    a.seg[1] = {aggS2, Wl1 + 2 * 4096, 64};
    a.seg[2] = {aggS4, Wl1 + 4 * 4096, 64};
    a.seg[3] = {aggS6, Wl1 + 6 * 4096, 64};
    a.seg[4] = {x0s, Wr1 + 0 * 4096, 64};
    a.seg[5] = {x0s, Wr1 + 2 * 4096, 64};
    a.seg[6] = {x0s, Wr1 + 4 * 4096, 64};
    a.seg[7] = {x0s, Wr1 + 6 * 4096, 64};
    a.nseg = 8;
    a.bias[0] = bl1 + 0 * 64; a.bias[1] = bl1 + 2 * 64;
    a.bias[2] = bl1 + 4 * 64; a.bias[3] = bl1 + 6 * 64; a.nbias = 4;
    a.out = x1s; a.M = NS; a.relu = 1;
    seg_gemm<<<(NS + 63) / 64, 256, 0, stream>>>(a);
  }
  // users (agg1 aliases aggS0/aggS2 -- series GEMM already consumed them)
  agg_csr_k<<<(NU * 64 + 255) / 256, 256, 0, stream>>>(adj1, off1, x0s, agg1, NU);
  {
    GemmArgs a{};
    a.seg[0] = {agg1, Wl1 + 1 * 4096, 64};
    a.seg[1] = {x0u, Wr1 + 1 * 4096, 64};
    a.nseg = 2;
    a.bias[0] = bl1 + 1 * 64; a.nbias = 1;
    a.out = x1u; a.M = NU; a.relu = 1;
    seg_gemm<<<(NU + 63) / 64, 256, 0, stream>>>(a);
  }
  // genres (direct small)
  agg_small_k<<<128, 256, 0, stream>>>(e_g2s + E_g, e_g2s, E_g, x0s, agg3, cnt3, NG, 128);
  fin_small_k<<<(NG * CDIM + 255) / 256, 256, 0, stream>>>(agg3, cnt3, NG);
  {
    GemmArgs a{};
    a.seg[0] = {agg3, Wl1 + 3 * 4096, 64};
    a.seg[1] = {g_emb, Wr1 + 3 * 4096, 64};
    a.nseg = 2;
    a.bias[0] = bl1 + 3 * 64; a.nbias = 1;
    a.out = x1g; a.M = NG; a.relu = 1;
    seg_gemm<<<(NG + 63) / 64, 256, 0, stream>>>(a);
  }
  // writer (CSR, bucketed type 4 = edge type 5 s->w)
  agg_csr_k<<<(NW * 64 + 255) / 256, 256, 0, stream>>>(adj4, off4, x0s, agg5, NW);
  {
    GemmArgs a{};
    a.seg[0] = {agg5, Wl1 + 5 * 4096, 64};
    a.seg[1] = {w_emb, Wr1 + 5 * 4096, 64};
    a.nseg = 2;
    a.bias[0] = bl1 + 5 * 64; a.nbias = 1;
    a.out = x1w; a.M = NW; a.relu = 1;
    seg_gemm<<<(NW + 63) / 64, 256, 0, stream>>>(a);
  }
  // type (direct small)
  agg_small_k<<<64, 256, 0, stream>>>(e_t2s + E_t, e_t2s, E_t, x0s, agg7, cnt7, NT, 64);
  fin_small_k<<<(NT * CDIM + 255) / 256, 256, 0, stream>>>(agg7, cnt7, NT);
  {
    GemmArgs a{};
    a.seg[0] = {agg7, Wl1 + 7 * 4096, 64};
    a.seg[1] = {t_emb, Wr1 + 7 * 4096, 64};
    a.nseg = 2;
    a.bias[0] = bl1 + 7 * 64; a.nbias = 1;
    a.out = x1t; a.M = NT; a.relu = 1;
    seg_gemm<<<(NT + 63) / 64, 256, 0, stream>>>(a);
  }

  // ---- layer 2 ----
  agg_csr_k<<<(NS * 64 + 255) / 256, 256, 0, stream>>>(adj0, off0, x1u, aggS0, NS);
  agg_csr_k<<<(NS * 64 + 255) / 256, 256, 0, stream>>>(adj2, off2, x1g, aggS2, NS);
  agg_csr_k<<<(NS * 64 + 255) / 256, 256, 0, stream>>>(adj3, off3, x1w, aggS4, NS);
  agg_csr_k<<<(NS * 64 + 255) / 256, 256, 0, stream>>>(adj5, off5, x1t, aggS6, NS);
  {  // series -> x2s
    GemmArgs a{};
    a.seg[0] = {aggS0, Wl2 + 0 * 4096, 64};
    a.seg[1] = {aggS2, Wl2 + 2 * 4096, 64};
    a.seg[2] = {aggS4, Wl2 + 4 * 4096, 64};
    a.seg[3] = {aggS6, Wl2 + 6 * 4096, 64};
    a.seg[4] = {x1s, Wr2 + 0 * 4096, 64};
    a.seg[5] = {x1s, Wr2 + 2 * 4096, 64};
    a.seg[6] = {x1s, Wr2 + 4 * 4096, 64};
    a.seg[7] = {x1s, Wr2 + 6 * 4096, 64};
    a.nseg = 8;
    a.bias[0] = bl2 + 0 * 64; a.bias[1] = bl2 + 2 * 64;
    a.bias[2] = bl2 + 4 * 64; a.bias[3] = bl2 + 6 * 64; a.nbias = 4;
    a.out = x2s; a.M = NS; a.relu = 0;
    seg_gemm<<<(NS + 63) / 64, 256, 0, stream>>>(a);
  }
  agg_csr_k<<<(NU * 64 + 255) / 256, 256, 0, stream>>>(adj1, off1, x1s, agg1, NU);
  {  // users -> x2u
    GemmArgs a{};
    a.seg[0] = {agg1, Wl2 + 1 * 4096, 64};
    a.seg[1] = {x1u, Wr2 + 1 * 4096, 64};
    a.nseg = 2;
    a.bias[0] = bl2 + 1 * 64; a.nbias = 1;
    a.out = x2u; a.M = NU; a.relu = 0;
    seg_gemm<<<(NU + 63) / 64, 256, 0, stream>>>(a);
  }

  // ---- scoring ----
  score_k<<<((long long)E_l * 64 + 255) / 256, 256, 0, stream>>>(
      eli, E_l, x2u, x2s, (float*)d_out);
}

// Round 6
// 1190.605 us; speedup vs baseline: 2.7283x; 1.1256x over previous
//
#include <hip/hip_runtime.h>

#define NU 100000
#define NS 50000
#define NG 50
#define NW 20000
#define NT 10
#define CDIM 64
#define FDIM 384

typedef short bf16x8 __attribute__((ext_vector_type(8)));
typedef float f32x4 __attribute__((ext_vector_type(4)));
typedef unsigned short ushort;
typedef unsigned int uint;

// ---- dst-chunk bucketing (6 bucketed edge types; types 3,7 handled direct) --
#define CHUNK 128
#define CSHIFT 7
#define CMASK 127
#define NBINS 2503      // 391+782+391+391+157+391
#define PSTRIDE 800
#define BTOT 352
#define CTOT 2503

struct PrepArgs {
  const int* src[6];
  const int* dst[6];
  int E[6];
  int nchunk[6];
  int nb[6];
  int cbase[7];
  int bbase[7];
  int cstart[7];
  int* partial;   // [BTOT][PSTRIDE]
  int* chunktot;  // [NBINS]
  int* choff;     // [NBINS + 6]
  int* bucket[6];
  int* adj[6];
  int* off[6];
};

__global__ __launch_bounds__(256) void hist_k(PrepArgs a) {
  __shared__ int bins[PSTRIDE];
  int b = blockIdx.x, t = threadIdx.x;
  int ty = 0;
  while (b >= a.bbase[ty + 1]) ++ty;
  int bl = b - a.bbase[ty], B = a.bbase[ty + 1] - a.bbase[ty];
  int n = a.nchunk[ty], E = a.E[ty];
  const int* __restrict__ dst = a.dst[ty];
  for (int i = t; i < n; i += 256) bins[i] = 0;
  __syncthreads();
  for (int i = bl * 256 + t; i < E; i += B * 256) atomicAdd(&bins[dst[i] >> CSHIFT], 1);
  __syncthreads();
  int* row = a.partial + (size_t)b * PSTRIDE;
  for (int i = t; i < n; i += 256) row[i] = bins[i];
}

__global__ __launch_bounds__(256) void scanb_k(PrepArgs a) {
  int bin = blockIdx.x * 256 + threadIdx.x;
  if (bin >= NBINS) return;
  int ty = 0;
  while (bin >= a.cbase[ty + 1]) ++ty;
  int l = bin - a.cbase[ty];
  int run = 0;
  for (int b = a.bbase[ty]; b < a.bbase[ty + 1]; ++b) {
    int* p = a.partial + (size_t)b * PSTRIDE + l;
    int v = *p;
    *p = run;
    run += v;
  }
  a.chunktot[bin] = run;
}

__global__ __launch_bounds__(1024) void scanc_k(PrepArgs a) {
  __shared__ int sc[1024];
  int ty = blockIdx.x, t = threadIdx.x;
  int n = a.nchunk[ty];
  int v = (t < n) ? a.chunktot[a.cbase[ty] + t] : 0;
  sc[t] = v;
  __syncthreads();
  for (int d = 1; d < 1024; d <<= 1) {
    int u = (t >= d) ? sc[t - d] : 0;
    __syncthreads();
    sc[t] += u;
    __syncthreads();
  }
  int* choff = a.choff + a.cbase[ty] + ty;
  if (t < n) choff[t] = sc[t] - v;
  if (t == n - 1) choff[n] = sc[t];
}

__global__ __launch_bounds__(256) void fill_k(PrepArgs a) {
  __shared__ int bins[PSTRIDE];
  __shared__ int base[PSTRIDE];
  int b = blockIdx.x, t = threadIdx.x;
  int ty = 0;
  while (b >= a.bbase[ty + 1]) ++ty;
  int bl = b - a.bbase[ty], B = a.bbase[ty + 1] - a.bbase[ty];
  int n = a.nchunk[ty], E = a.E[ty];
  const int* __restrict__ dst = a.dst[ty];
  const int* __restrict__ src = a.src[ty];
  int* __restrict__ bucket = a.bucket[ty];
  const int* choff = a.choff + a.cbase[ty] + ty;
  const int* prow = a.partial + (size_t)b * PSTRIDE;
  for (int i = t; i < n; i += 256) { bins[i] = 0; base[i] = choff[i] + prow[i]; }
  __syncthreads();
  for (int i = bl * 256 + t; i < E; i += B * 256) {
    int d = dst[i];
    int l = d >> CSHIFT;
    int r = atomicAdd(&bins[l], 1);
    bucket[base[l] + r] = (src[i] << CSHIFT) | (d & CMASK);
  }
}

__global__ __launch_bounds__(256) void csr_k(PrepArgs a) {
  __shared__ int bins[CHUNK];
  __shared__ int sc[CHUNK];
  __shared__ int basea[CHUNK];
  int b = blockIdx.x, t = threadIdx.x;
  int ty = 0;
  while (b >= a.cstart[ty + 1]) ++ty;
  int c = b - a.cstart[ty];
  const int* __restrict__ bucket = a.bucket[ty];
  const int* choff = a.choff + a.cbase[ty] + ty;
  int beg = choff[c], end = choff[c + 1];
  if (t < CHUNK) bins[t] = 0;
  __syncthreads();
  for (int i = beg + t; i < end; i += 256) atomicAdd(&bins[bucket[i] & CMASK], 1);
  __syncthreads();
  int v = (t < CHUNK) ? bins[t] : 0;
  if (t < CHUNK) sc[t] = v;
  __syncthreads();
#pragma unroll
  for (int d = 1; d < CHUNK; d <<= 1) {
    int u = (t < CHUNK && t >= d) ? sc[t - d] : 0;
    __syncthreads();
    if (t < CHUNK) sc[t] += u;
    __syncthreads();
  }
  if (t < CHUNK) { basea[t] = beg + sc[t] - v; bins[t] = basea[t]; }
  __syncthreads();
  int gbase = c * CHUNK;
  int nb = a.nb[ty];
  if (t < CHUNK && gbase + t < nb) a.off[ty][gbase + t] = basea[t];
  if (b == a.cstart[ty + 1] - 1 && t == 0) a.off[ty][nb] = choff[a.nchunk[ty]];
  int* __restrict__ adj = a.adj[ty];
  for (int i = beg + t; i < end; i += 256) {
    int pk = bucket[i];
    int r = atomicAdd(&bins[pk & CMASK], 1);
    adj[r] = pk >> CSHIFT;
  }
}

// ---------------------------------------------------------------------------
// CSR gather aggregation (mean fused): one wave per dst node, lane = channel.
// ---------------------------------------------------------------------------
__device__ __forceinline__ void csr_gather_body(const int* __restrict__ adj,
                                                const int* __restrict__ off,
                                                const float* __restrict__ x,
                                                float* __restrict__ out,
                                                int wid, int lane) {
  int beg = off[wid], deg = off[wid + 1] - beg;
  float a0 = 0.f, a1 = 0.f, a2 = 0.f, a3 = 0.f;
  int j = 0;
  for (; j + 4 <= deg; j += 4) {
    int s0 = adj[beg + j], s1 = adj[beg + j + 1];
    int s2 = adj[beg + j + 2], s3 = adj[beg + j + 3];
    a0 += x[(size_t)s0 * CDIM + lane];
    a1 += x[(size_t)s1 * CDIM + lane];
    a2 += x[(size_t)s2 * CDIM + lane];
    a3 += x[(size_t)s3 * CDIM + lane];
  }
  for (; j < deg; ++j) a0 += x[(size_t)adj[beg + j] * CDIM + lane];
  float s = (a0 + a1) + (a2 + a3);
  out[(size_t)wid * CDIM + lane] = (deg > 0) ? s / (float)deg : 0.f;
}

__global__ __launch_bounds__(256) void agg_csr_k(const int* __restrict__ adj,
                                                 const int* __restrict__ off,
                                                 const float* __restrict__ x,
                                                 float* __restrict__ out, int N) {
  int wid = (blockIdx.x * 256 + threadIdx.x) >> 6;
  int lane = threadIdx.x & 63;
  if (wid >= N) return;
  csr_gather_body(adj, off, x, out, wid, lane);
}

// Fused multi-set CSR aggregation (all sets N=NS).
struct MAgg {
  const int* adj[4];
  const int* off[4];
  const float* x[4];
  float* out[4];
};
__global__ __launch_bounds__(256) void agg_multi_k(MAgg a) {
  int set = blockIdx.y;
  int wid = (blockIdx.x * 256 + threadIdx.x) >> 6;
  int lane = threadIdx.x & 63;
  if (wid >= NS) return;
  csr_gather_body(a.adj[set], a.off[set], a.x[set], a.out[set], wid, lane);
}

// ---------------------------------------------------------------------------
// Small-dst aggregation (genres=50, type=10): two-stage, no global atomics.
// ---------------------------------------------------------------------------
__global__ __launch_bounds__(256) void agg_small1(const int* __restrict__ src,
                                                  const int* __restrict__ dst, int E,
                                                  const float* __restrict__ x,
                                                  float* __restrict__ partial,
                                                  int* __restrict__ pcnt, int nd, int G) {
  __shared__ float acc[NG * CDIM];
  __shared__ int cnt[NG];
  int t = threadIdx.x, lane = t & 63, wv = t >> 6;
  for (int i = t; i < nd * CDIM; i += 256) acc[i] = 0.f;
  for (int i = t; i < nd; i += 256) cnt[i] = 0;
  __syncthreads();
  for (int j0 = (blockIdx.x * 4 + wv) * 64; j0 < E; j0 += G * 256) {
    int myj = j0 + lane;
    int s = 0, d = 0;
    if (myj < E) { s = src[myj]; d = dst[myj]; }
    int m = min(64, E - j0);
    int j = 0;
    for (; j + 4 <= m; j += 4) {
      int s0 = __shfl(s, j, 64), s1 = __shfl(s, j + 1, 64);
      int s2 = __shfl(s, j + 2, 64), s3 = __shfl(s, j + 3, 64);
      int d0 = __shfl(d, j, 64), d1 = __shfl(d, j + 1, 64);
      int d2 = __shfl(d, j + 2, 64), d3 = __shfl(d, j + 3, 64);
      float v0 = x[(size_t)s0 * CDIM + lane];
      float v1 = x[(size_t)s1 * CDIM + lane];
      float v2 = x[(size_t)s2 * CDIM + lane];
      float v3 = x[(size_t)s3 * CDIM + lane];
      atomicAdd(&acc[d0 * CDIM + lane], v0);
      atomicAdd(&acc[d1 * CDIM + lane], v1);
      atomicAdd(&acc[d2 * CDIM + lane], v2);
      atomicAdd(&acc[d3 * CDIM + lane], v3);
      if (lane == 0) {
        atomicAdd(&cnt[d0], 1); atomicAdd(&cnt[d1], 1);
        atomicAdd(&cnt[d2], 1); atomicAdd(&cnt[d3], 1);
      }
    }
    for (; j < m; ++j) {
      int sj = __shfl(s, j, 64), dj = __shfl(d, j, 64);
      atomicAdd(&acc[dj * CDIM + lane], x[(size_t)sj * CDIM + lane]);
      if (lane == 0) atomicAdd(&cnt[dj], 1);
    }
  }
  __syncthreads();
  float* po = partial + (size_t)blockIdx.x * nd * CDIM;
  for (int i = t; i < nd * CDIM; i += 256) po[i] = acc[i];
  int* pc = pcnt + blockIdx.x * nd;
  for (int i = t; i < nd; i += 256) pc[i] = cnt[i];
}

__global__ __launch_bounds__(256) void agg_small2(const float* __restrict__ partial,
                                                  const int* __restrict__ pcnt,
                                                  float* __restrict__ out, int nd, int G) {
  __shared__ float red[4][CDIM];
  __shared__ int redc[4];
  int d = blockIdx.x, t = threadIdx.x, c = t & 63, sl = t >> 6;
  float s = 0.f;
  int k = 0;
  for (int g = sl; g < G; g += 4) {
    s += partial[(size_t)g * nd * CDIM + d * CDIM + c];
    if (c == 0) k += pcnt[g * nd + d];
  }
  red[sl][c] = s;
  if (c == 0) redc[sl] = k;
  __syncthreads();
  if (sl == 0) {
    float tot = red[0][c] + red[1][c] + red[2][c] + red[3][c];
    int kt = redc[0] + redc[1] + redc[2] + redc[3];
    out[d * CDIM + c] = (kt > 0) ? tot / (float)kt : 0.f;
  }
}

// ---------------------------------------------------------------------------
// Weight prep: split all weights into bf16 hi/lo planes (once per launch).
// Also pre-sums Wr over series edge types (segs 0,2,4,6) per layer.
// Layout (ushort units): WuH=0 WuL=24576 WsH=49152 WsL=73728; per layer at
// base=98304+layer*139264: WlH[8*4096] WlL WrH[8*4096] WrL WrsH[4096] WrsL.
// Total = 376832 ushorts = 188416 floats.
// ---------------------------------------------------------------------------
#define W_TOTAL 188416
__global__ __launch_bounds__(256) void wprep_k(const float* __restrict__ Wu,
                                               const float* __restrict__ Wsp,
                                               const float* __restrict__ Wl1,
                                               const float* __restrict__ Wr1,
                                               const float* __restrict__ Wl2,
                                               const float* __restrict__ Wr2,
                                               ushort* __restrict__ S) {
  int i = blockIdx.x * 256 + threadIdx.x;
  if (i >= W_TOTAL) return;
  float v;
  size_t hoff, loff;
  if (i < 24576) { v = Wu[i]; hoff = i; loff = 24576 + (size_t)i; }
  else if (i < 49152) { int j = i - 24576; v = Wsp[j]; hoff = 49152 + (size_t)j; loff = 73728 + (size_t)j; }
  else {
    int j = i - 49152;
    int layer = j / 69632;
    j %= 69632;
    const float* Wl = layer ? Wl2 : Wl1;
    const float* Wr = layer ? Wr2 : Wr1;
    size_t base = 98304 + (size_t)layer * 139264;
    if (j < 32768) { v = Wl[j]; hoff = base + j; loff = base + 32768 + j; }
    else if (j < 65536) { int q = j - 32768; v = Wr[q]; hoff = base + 65536 + q; loff = base + 98304 + q; }
    else {
      int q = j - 65536;
      v = Wr[0 * 4096 + q] + Wr[2 * 4096 + q] + Wr[4 * 4096 + q] + Wr[6 * 4096 + q];
      hoff = base + 131072 + q; loff = base + 135168 + q;
    }
  }
  uint u = __float_as_uint(v);
  uint h = u & 0xFFFF0000u;
  float r = v - __uint_as_float(h);
  S[hoff] = (ushort)(h >> 16);
  S[loff] = (ushort)(__float_as_uint(r) >> 16);
}

// ---------------------------------------------------------------------------
// MFMA segmented GEMM (bf16 hi/lo split, 3-term: AhBh + AlBh + AhBl).
// out[m,c] = relu?( sum_seg sum_k A[m,k]*W[c,k] + bias ). No LDS, no barriers.
// 64(M)x64(N) per block, 4 waves (wave = 16 M-rows), 4 n-tiles/wave.
// ---------------------------------------------------------------------------
struct GSeg { const float* A; const ushort* Wh; const ushort* Wl; int F; };
struct GArgs {
  GSeg seg[5];
  const float* bias[4];
  float* out;
  int nseg, nbias, M, relu;
};

__device__ __forceinline__ void split8(const float* __restrict__ p, bf16x8& hi, bf16x8& lo) {
  float4 v0 = *(const float4*)p;
  float4 v1 = *(const float4*)(p + 4);
  float a[8] = {v0.x, v0.y, v0.z, v0.w, v1.x, v1.y, v1.z, v1.w};
  union { uint u[4]; bf16x8 v; } H, L;
#pragma unroll
  for (int i = 0; i < 4; ++i) {
    uint u0 = __float_as_uint(a[2 * i]), u1 = __float_as_uint(a[2 * i + 1]);
    uint h0 = u0 & 0xFFFF0000u, h1 = u1 & 0xFFFF0000u;
    float r0 = a[2 * i] - __uint_as_float(h0);
    float r1 = a[2 * i + 1] - __uint_as_float(h1);
    H.u[i] = (h0 >> 16) | h1;
    L.u[i] = ((__float_as_uint(r0) & 0xFFFF0000u) >> 16) | (__float_as_uint(r1) & 0xFFFF0000u);
  }
  hi = H.v;
  lo = L.v;
}

__global__ __launch_bounds__(256) void mfma_gemm(GArgs g) {
  const int tid = threadIdx.x;
  const int lane = tid & 63, wv = tid >> 6;
  const int ln = lane & 15, quad = lane >> 4;
  const int m0 = blockIdx.x * 64;
  f32x4 acc[4];
#pragma unroll
  for (int nt = 0; nt < 4; ++nt) acc[nt] = (f32x4){0.f, 0.f, 0.f, 0.f};

  const int ar = min(m0 + 16 * wv + ln, g.M - 1);  // A-frag row (clamped)

  for (int s = 0; s < g.nseg; ++s) {
    const float* __restrict__ A = g.seg[s].A;
    const ushort* __restrict__ Wh = g.seg[s].Wh;
    const ushort* __restrict__ Wl = g.seg[s].Wl;
    const int F = g.seg[s].F;
    const float* ap = A + (size_t)ar * F + quad * 8;
    const ushort* whp = Wh + (size_t)ln * F + quad * 8;
    const ushort* wlp = Wl + (size_t)ln * F + quad * 8;
    for (int k0 = 0; k0 < F; k0 += 32) {
      bf16x8 ah, al;
      split8(ap + k0, ah, al);
#pragma unroll
      for (int nt = 0; nt < 4; ++nt) {
        bf16x8 bh = *(const bf16x8*)(whp + (size_t)nt * 16 * F + k0);
        bf16x8 bl = *(const bf16x8*)(wlp + (size_t)nt * 16 * F + k0);
        acc[nt] = __builtin_amdgcn_mfma_f32_16x16x32_bf16(ah, bh, acc[nt], 0, 0, 0);
        acc[nt] = __builtin_amdgcn_mfma_f32_16x16x32_bf16(al, bh, acc[nt], 0, 0, 0);
        acc[nt] = __builtin_amdgcn_mfma_f32_16x16x32_bf16(ah, bl, acc[nt], 0, 0, 0);
      }
    }
  }

#pragma unroll
  for (int nt = 0; nt < 4; ++nt) {
    int c = nt * 16 + ln;
    float b = 0.f;
    for (int i = 0; i < g.nbias; ++i) b += g.bias[i][c];
#pragma unroll
    for (int r = 0; r < 4; ++r) {
      int m = m0 + 16 * wv + quad * 4 + r;
      if (m < g.M) {
        float o = acc[nt][r] + b;
        if (g.relu) o = fmaxf(o, 0.f);
        g.out[(size_t)m * CDIM + c] = o;
      }
    }
  }
}

// ---------------------------------------------------------------------------
// Edge scoring: one wave per edge, wave-reduce dot over 64 channels.
// ---------------------------------------------------------------------------
__global__ __launch_bounds__(256) void score_k(const int* __restrict__ eli, int E,
                                               const float* __restrict__ xu,
                                               const float* __restrict__ xs,
                                               float* __restrict__ out) {
  long long gid = (long long)blockIdx.x * 256 + threadIdx.x;
  int e = (int)(gid >> 6);
  int c = (int)(gid & 63);
  if (e < E) {
    int u = eli[e];
    int sv = eli[E + e];
    float p = xu[(size_t)u * CDIM + c] * xs[(size_t)sv * CDIM + c];
#pragma unroll
    for (int off = 32; off > 0; off >>= 1) p += __shfl_down(p, off, 64);
    if (c == 0) out[e] = p;
  }
}

extern "C" void kernel_launch(void* const* d_in, const int* in_sizes, int n_in,
                              void* d_out, int out_size, void* d_ws, size_t ws_size,
                              hipStream_t stream) {
  const float* reviews  = (const float*)d_in[0];
  const float* overview = (const float*)d_in[1];
  const float* g_emb    = (const float*)d_in[2];
  const float* w_emb    = (const float*)d_in[3];
  const float* t_emb    = (const float*)d_in[4];
  const float* Wu  = (const float*)d_in[5];
  const float* bu  = (const float*)d_in[6];
  const float* Wsp = (const float*)d_in[7];
  const float* bs  = (const float*)d_in[8];
  const float* Wl1 = (const float*)d_in[9];
  const float* bl1 = (const float*)d_in[10];
  const float* Wr1 = (const float*)d_in[11];
  const float* Wl2 = (const float*)d_in[12];
  const float* bl2 = (const float*)d_in[13];
  const float* Wr2 = (const float*)d_in[14];
  const int* e_u2s = (const int*)d_in[15];
  const int* e_g2s = (const int*)d_in[16];
  const int* e_w2s = (const int*)d_in[17];
  const int* e_t2s = (const int*)d_in[18];
  const int* eli   = (const int*)d_in[19];
  const int E_u = in_sizes[15] / 2;
  const int E_g = in_sizes[16] / 2;
  const int E_w = in_sizes[17] / 2;
  const int E_t = in_sizes[18] / 2;
  const int E_l = in_sizes[19] / 2;

  // ---- workspace layout (4B units) ----
  float* ws = (float*)d_ws;
  size_t off = 0;
  auto take = [&](size_t n) { float* p = ws + off; off += n; return p; };
  float* x0u = take((size_t)NU * CDIM);
  float* x0s = take((size_t)NS * CDIM);
  float* x1u = take((size_t)NU * CDIM);
  float* x1s = take((size_t)NS * CDIM);
  float* x1g = take((size_t)NG * CDIM);
  float* x1w = take((size_t)NW * CDIM);
  float* x1t = take((size_t)NT * CDIM);
  float* aggS0 = take((size_t)NS * CDIM);
  float* aggS2 = take((size_t)NS * CDIM);
  float* aggS4 = take((size_t)NS * CDIM);
  float* aggS6 = take((size_t)NS * CDIM);
  float* agg1  = aggS0;  // NU*CDIM alias over aggS0+aggS2 (disjoint lifetime)
  float* agg5  = take((size_t)NW * CDIM);
  float* agg3  = take((size_t)NG * CDIM);
  float* agg7  = take((size_t)NT * CDIM);
  // small-agg partials (shared genres/type, sequential use)
  float* spart = take((size_t)256 * NG * CDIM);
  int* spcnt   = (int*)take((size_t)256 * NG);
  // split weights: 2*W_TOTAL ushorts = W_TOTAL floats
  ushort* wsplit = (ushort*)take((size_t)W_TOTAL);
  // buckets + CSR (types 0,1,2,4,5,6)
  int* bkt0 = (int*)take(E_u);
  int* bkt1 = (int*)take(E_u);
  int* bkt2 = (int*)take(E_g);
  int* bkt3 = (int*)take(E_w);
  int* bkt4 = (int*)take(E_w);
  int* bkt5 = (int*)take(E_t);
  int* adj0 = (int*)take(E_u);
  int* adj1 = (int*)take(E_u);
  int* adj2 = (int*)take(E_g);
  int* adj3 = (int*)take(E_w);
  int* adj4 = (int*)take(E_w);
  int* adj5 = (int*)take(E_t);
  int* off0 = (int*)take(NS + 1);
  int* off1 = (int*)take(NU + 1);
  int* off2 = (int*)take(NS + 1);
  int* off3 = (int*)take(NS + 1);
  int* off4 = (int*)take(NW + 1);
  int* off5 = (int*)take(NS + 1);
  int* partial  = (int*)take((size_t)BTOT * PSTRIDE);
  int* chunktot = (int*)take(NBINS);
  int* choffG   = (int*)take(NBINS + 6);
  float* x2u = x0u;
  float* x2s = x0s;

  // split-weight offsets (ushort units)
  const ushort* WuH = wsplit + 0;
  const ushort* WuL = wsplit + 24576;
  const ushort* WsH = wsplit + 49152;
  const ushort* WsL = wsplit + 73728;
  auto WlH = [&](int layer, int seg) { return wsplit + 98304 + (size_t)layer * 139264 + (size_t)seg * 4096; };
  auto WlL = [&](int layer, int seg) { return wsplit + 98304 + (size_t)layer * 139264 + 32768 + (size_t)seg * 4096; };
  auto WrH = [&](int layer, int seg) { return wsplit + 98304 + (size_t)layer * 139264 + 65536 + (size_t)seg * 4096; };
  auto WrL = [&](int layer, int seg) { return wsplit + 98304 + (size_t)layer * 139264 + 98304 + (size_t)seg * 4096; };
  auto WrsH = [&](int layer) { return wsplit + 98304 + (size_t)layer * 139264 + 131072; };
  auto WrsL = [&](int layer) { return wsplit + 98304 + (size_t)layer * 139264 + 135168; };

  // ---- prep args ----
  PrepArgs pa{};
  const int* bsrc[6] = {e_u2s, e_u2s + E_u, e_g2s, e_w2s, e_w2s + E_w, e_t2s};
  const int* bdst[6] = {e_u2s + E_u, e_u2s, e_g2s + E_g, e_w2s + E_w, e_w2s, e_t2s + E_t};
  int bE[6]  = {E_u, E_u, E_g, E_w, E_w, E_t};
  int nch[6] = {391, 782, 391, 391, 157, 391};
  int cb[7]  = {0, 391, 1173, 1564, 1955, 2112, 2503};
  int bpt[6] = {128, 128, 32, 16, 16, 32};
  int nbT[6] = {NS, NU, NS, NS, NW, NS};
  int* bkts[6] = {bkt0, bkt1, bkt2, bkt3, bkt4, bkt5};
  int* adjs[6] = {adj0, adj1, adj2, adj3, adj4, adj5};
  int* offs[6] = {off0, off1, off2, off3, off4, off5};
  int bb = 0, cs = 0;
  for (int i = 0; i < 6; ++i) {
    pa.src[i] = bsrc[i]; pa.dst[i] = bdst[i]; pa.E[i] = bE[i];
    pa.nchunk[i] = nch[i]; pa.nb[i] = nbT[i]; pa.cbase[i] = cb[i];
    pa.bbase[i] = bb; bb += bpt[i];
    pa.cstart[i] = cs; cs += nch[i];
    pa.bucket[i] = bkts[i]; pa.adj[i] = adjs[i]; pa.off[i] = offs[i];
  }
  pa.cbase[6] = cb[6]; pa.bbase[6] = bb; pa.cstart[6] = cs;
  pa.partial = partial; pa.chunktot = chunktot; pa.choff = choffG;

  // ---- prep + weight split ----
  wprep_k<<<(W_TOTAL + 255) / 256, 256, 0, stream>>>(Wu, Wsp, Wl1, Wr1, Wl2, Wr2, wsplit);
  hist_k<<<BTOT, 256, 0, stream>>>(pa);
  scanb_k<<<(NBINS + 255) / 256, 256, 0, stream>>>(pa);
  scanc_k<<<6, 1024, 0, stream>>>(pa);
  fill_k<<<BTOT, 256, 0, stream>>>(pa);
  csr_k<<<CTOT, 256, 0, stream>>>(pa);

  // embedding-driven series aggs (3 sets fused)
  {
    MAgg a{};
    a.adj[0] = adj2; a.off[0] = off2; a.x[0] = g_emb; a.out[0] = aggS2;
    a.adj[1] = adj3; a.off[1] = off3; a.x[1] = w_emb; a.out[1] = aggS4;
    a.adj[2] = adj5; a.off[2] = off5; a.x[2] = t_emb; a.out[2] = aggS6;
    dim3 grid((NS * 64 + 255) / 256, 3);
    agg_multi_k<<<grid, 256, 0, stream>>>(a);
  }

  // ---- projections ----
  {
    GArgs a{};
    a.seg[0] = {reviews, WuH, WuL, FDIM}; a.nseg = 1;
    a.bias[0] = bu; a.nbias = 1;
    a.out = x0u; a.M = NU; a.relu = 0;
    mfma_gemm<<<(NU + 63) / 64, 256, 0, stream>>>(a);
  }
  {
    GArgs a{};
    a.seg[0] = {overview, WsH, WsL, FDIM}; a.nseg = 1;
    a.bias[0] = bs; a.nbias = 1;
    a.out = x0s; a.M = NS; a.relu = 0;
    mfma_gemm<<<(NS + 63) / 64, 256, 0, stream>>>(a);
  }

  // ---- layer 1 ----
  agg_csr_k<<<(NS * 64 + 255) / 256, 256, 0, stream>>>(adj0, off0, x0u, aggS0, NS);
  {  // series (4 Wl segs + x0s * sum(Wr))
    GArgs a{};
    a.seg[0] = {aggS0, WlH(0, 0), WlL(0, 0), 64};
    a.seg[1] = {aggS2, WlH(0, 2), WlL(0, 2), 64};
    a.seg[2] = {aggS4, WlH(0, 4), WlL(0, 4), 64};
    a.seg[3] = {aggS6, WlH(0, 6), WlL(0, 6), 64};
    a.seg[4] = {x0s, WrsH(0), WrsL(0), 64};
    a.nseg = 5;
    a.bias[0] = bl1 + 0 * 64; a.bias[1] = bl1 + 2 * 64;
    a.bias[2] = bl1 + 4 * 64; a.bias[3] = bl1 + 6 * 64; a.nbias = 4;
    a.out = x1s; a.M = NS; a.relu = 1;
    mfma_gemm<<<(NS + 63) / 64, 256, 0, stream>>>(a);
  }
  agg_csr_k<<<(NU * 64 + 255) / 256, 256, 0, stream>>>(adj1, off1, x0s, agg1, NU);
  {  // users
    GArgs a{};
    a.seg[0] = {agg1, WlH(0, 1), WlL(0, 1), 64};
    a.seg[1] = {x0u, WrH(0, 1), WrL(0, 1), 64};
    a.nseg = 2;
    a.bias[0] = bl1 + 1 * 64; a.nbias = 1;
    a.out = x1u; a.M = NU; a.relu = 1;
    mfma_gemm<<<(NU + 63) / 64, 256, 0, stream>>>(a);
  }
  // genres (two-stage small)
  agg_small1<<<256, 256, 0, stream>>>(e_g2s + E_g, e_g2s, E_g, x0s, spart, spcnt, NG, 256);
  agg_small2<<<NG, 256, 0, stream>>>(spart, spcnt, agg3, NG, 256);
  {
    GArgs a{};
    a.seg[0] = {agg3, WlH(0, 3), WlL(0, 3), 64};
    a.seg[1] = {g_emb, WrH(0, 3), WrL(0, 3), 64};
    a.nseg = 2;
    a.bias[0] = bl1 + 3 * 64; a.nbias = 1;
    a.out = x1g; a.M = NG; a.relu = 1;
    mfma_gemm<<<1, 256, 0, stream>>>(a);
  }
  // writer (CSR)
  agg_csr_k<<<(NW * 64 + 255) / 256, 256, 0, stream>>>(adj4, off4, x0s, agg5, NW);
  {
    GArgs a{};
    a.seg[0] = {agg5, WlH(0, 5), WlL(0, 5), 64};
    a.seg[1] = {w_emb, WrH(0, 5), WrL(0, 5), 64};
    a.nseg = 2;
    a.bias[0] = bl1 + 5 * 64; a.nbias = 1;
    a.out = x1w; a.M = NW; a.relu = 1;
    mfma_gemm<<<(NW + 63) / 64, 256, 0, stream>>>(a);
  }
  // type (two-stage small)
  agg_small1<<<128, 256, 0, stream>>>(e_t2s + E_t, e_t2s, E_t, x0s, spart, spcnt, NT, 128);
  agg_small2<<<NT, 256, 0, stream>>>(spart, spcnt, agg7, NT, 128);
  {
    GArgs a{};
    a.seg[0] = {agg7, WlH(0, 7), WlL(0, 7), 64};
    a.seg[1] = {t_emb, WrH(0, 7), WrL(0, 7), 64};
    a.nseg = 2;
    a.bias[0] = bl1 + 7 * 64; a.nbias = 1;
    a.out = x1t; a.M = NT; a.relu = 1;
    mfma_gemm<<<1, 256, 0, stream>>>(a);
  }

  // ---- layer 2 ----
  {  // 4 series aggs fused
    MAgg a{};
    a.adj[0] = adj0; a.off[0] = off0; a.x[0] = x1u; a.out[0] = aggS0;
    a.adj[1] = adj2; a.off[1] = off2; a.x[1] = x1g; a.out[1] = aggS2;
    a.adj[2] = adj3; a.off[2] = off3; a.x[2] = x1w; a.out[2] = aggS4;
    a.adj[3] = adj5; a.off[3] = off5; a.x[3] = x1t; a.out[3] = aggS6;
    dim3 grid((NS * 64 + 255) / 256, 4);
    agg_multi_k<<<grid, 256, 0, stream>>>(a);
  }
  {  // series -> x2s
    GArgs a{};
    a.seg[0] = {aggS0, WlH(1, 0), WlL(1, 0), 64};
    a.seg[1] = {aggS2, WlH(1, 2), WlL(1, 2), 64};
    a.seg[2] = {aggS4, WlH(1, 4), WlL(1, 4), 64};
    a.seg[3] = {aggS6, WlH(1, 6), WlL(1, 6), 64};
    a.seg[4] = {x1s, WrsH(1), WrsL(1), 64};
    a.nseg = 5;
    a.bias[0] = bl2 + 0 * 64; a.bias[1] = bl2 + 2 * 64;
    a.bias[2] = bl2 + 4 * 64; a.bias[3] = bl2 + 6 * 64; a.nbias = 4;
    a.out = x2s; a.M = NS; a.relu = 0;
    mfma_gemm<<<(NS + 63) / 64, 256, 0, stream>>>(a);
  }
  agg_csr_k<<<(NU * 64 + 255) / 256, 256, 0, stream>>>(adj1, off1, x1s, agg1, NU);
  {  // users -> x2u
    GArgs a{};
    a.seg[0] = {agg1, WlH(1, 1), WlL(1, 1), 64};
    a.seg[1] = {x1u, WrH(1, 1), WrL(1, 1), 64};
    a.nseg = 2;
    a.bias[0] = bl2 + 1 * 64; a.nbias = 1;
    a.out = x2u; a.M = NU; a.relu = 0;
    mfma_gemm<<<(NU + 63) / 64, 256, 0, stream>>>(a);
  }

  // ---- scoring ----
  score_k<<<((long long)E_l * 64 + 255) / 256, 256, 0, stream>>>(
      eli, E_l, x2u, x2s, (float*)d_out);
}

// Round 7
// 1070.464 us; speedup vs baseline: 3.0345x; 1.1122x over previous
//
#include <hip/hip_runtime.h>

#define NU 100000
#define NS 50000
#define NG 50
#define NW 20000
#define NT 10
#define CDIM 64
#define FDIM 384

typedef short bf16x8 __attribute__((ext_vector_type(8)));
typedef float f32x4 __attribute__((ext_vector_type(4)));
typedef unsigned short ushort;
typedef unsigned int uint;

// ---- dst-chunk bucketing (6 bucketed edge types; types 3,7 handled direct) --
#define CHUNK 128
#define CSHIFT 7
#define CMASK 127
#define NBINS 2503      // 391+782+391+391+157+391
#define PSTRIDE 800
#define BTOT 352
#define CTOT 2503

struct PrepArgs {
  const int* src[6];
  const int* dst[6];
  int E[6];
  int nchunk[6];
  int nb[6];
  int cbase[7];
  int bbase[7];
  int cstart[7];
  int* partial;   // [BTOT][PSTRIDE]
  int* chunktot;  // [NBINS]
  int* choff;     // [NBINS + 6]
  int* bucket[6];
  int* adj[6];
  int* off[6];
};

__global__ __launch_bounds__(256) void hist_k(PrepArgs a) {
  __shared__ int bins[PSTRIDE];
  int b = blockIdx.x, t = threadIdx.x;
  int ty = 0;
  while (b >= a.bbase[ty + 1]) ++ty;
  int bl = b - a.bbase[ty], B = a.bbase[ty + 1] - a.bbase[ty];
  int n = a.nchunk[ty], E = a.E[ty];
  const int* __restrict__ dst = a.dst[ty];
  for (int i = t; i < n; i += 256) bins[i] = 0;
  __syncthreads();
  for (int i = bl * 256 + t; i < E; i += B * 256) atomicAdd(&bins[dst[i] >> CSHIFT], 1);
  __syncthreads();
  int* row = a.partial + (size_t)b * PSTRIDE;
  for (int i = t; i < n; i += 256) row[i] = bins[i];
}

__global__ __launch_bounds__(256) void scanb_k(PrepArgs a) {
  int bin = blockIdx.x * 256 + threadIdx.x;
  if (bin >= NBINS) return;
  int ty = 0;
  while (bin >= a.cbase[ty + 1]) ++ty;
  int l = bin - a.cbase[ty];
  int run = 0;
  for (int b = a.bbase[ty]; b < a.bbase[ty + 1]; ++b) {
    int* p = a.partial + (size_t)b * PSTRIDE + l;
    int v = *p;
    *p = run;
    run += v;
  }
  a.chunktot[bin] = run;
}

__global__ __launch_bounds__(1024) void scanc_k(PrepArgs a) {
  __shared__ int sc[1024];
  int ty = blockIdx.x, t = threadIdx.x;
  int n = a.nchunk[ty];
  int v = (t < n) ? a.chunktot[a.cbase[ty] + t] : 0;
  sc[t] = v;
  __syncthreads();
  for (int d = 1; d < 1024; d <<= 1) {
    int u = (t >= d) ? sc[t - d] : 0;
    __syncthreads();
    sc[t] += u;
    __syncthreads();
  }
  int* choff = a.choff + a.cbase[ty] + ty;
  if (t < n) choff[t] = sc[t] - v;
  if (t == n - 1) choff[n] = sc[t];
}

__global__ __launch_bounds__(256) void fill_k(PrepArgs a) {
  __shared__ int bins[PSTRIDE];
  __shared__ int base[PSTRIDE];
  int b = blockIdx.x, t = threadIdx.x;
  int ty = 0;
  while (b >= a.bbase[ty + 1]) ++ty;
  int bl = b - a.bbase[ty], B = a.bbase[ty + 1] - a.bbase[ty];
  int n = a.nchunk[ty], E = a.E[ty];
  const int* __restrict__ dst = a.dst[ty];
  const int* __restrict__ src = a.src[ty];
  int* __restrict__ bucket = a.bucket[ty];
  const int* choff = a.choff + a.cbase[ty] + ty;
  const int* prow = a.partial + (size_t)b * PSTRIDE;
  for (int i = t; i < n; i += 256) { bins[i] = 0; base[i] = choff[i] + prow[i]; }
  __syncthreads();
  for (int i = bl * 256 + t; i < E; i += B * 256) {
    int d = dst[i];
    int l = d >> CSHIFT;
    int r = atomicAdd(&bins[l], 1);
    bucket[base[l] + r] = (src[i] << CSHIFT) | (d & CMASK);
  }
}

__global__ __launch_bounds__(256) void csr_k(PrepArgs a) {
  __shared__ int bins[CHUNK];
  __shared__ int sc[CHUNK];
  __shared__ int basea[CHUNK];
  int b = blockIdx.x, t = threadIdx.x;
  int ty = 0;
  while (b >= a.cstart[ty + 1]) ++ty;
  int c = b - a.cstart[ty];
  const int* __restrict__ bucket = a.bucket[ty];
  const int* choff = a.choff + a.cbase[ty] + ty;
  int beg = choff[c], end = choff[c + 1];
  if (t < CHUNK) bins[t] = 0;
  __syncthreads();
  for (int i = beg + t; i < end; i += 256) atomicAdd(&bins[bucket[i] & CMASK], 1);
  __syncthreads();
  int v = (t < CHUNK) ? bins[t] : 0;
  if (t < CHUNK) sc[t] = v;
  __syncthreads();
#pragma unroll
  for (int d = 1; d < CHUNK; d <<= 1) {
    int u = (t < CHUNK && t >= d) ? sc[t - d] : 0;
    __syncthreads();
    if (t < CHUNK) sc[t] += u;
    __syncthreads();
  }
  if (t < CHUNK) { basea[t] = beg + sc[t] - v; bins[t] = basea[t]; }
  __syncthreads();
  int gbase = c * CHUNK;
  int nb = a.nb[ty];
  if (t < CHUNK && gbase + t < nb) a.off[ty][gbase + t] = basea[t];
  if (b == a.cstart[ty + 1] - 1 && t == 0) a.off[ty][nb] = choff[a.nchunk[ty]];
  int* __restrict__ adj = a.adj[ty];
  for (int i = beg + t; i < end; i += 256) {
    int pk = bucket[i];
    int r = atomicAdd(&bins[pk & CMASK], 1);
    adj[r] = pk >> CSHIFT;
  }
}

// ---------------------------------------------------------------------------
// CSR gather aggregation (mean fused): one wave per dst node, lane = channel.
// ---------------------------------------------------------------------------
__device__ __forceinline__ void csr_gather_body(const int* __restrict__ adj,
                                                const int* __restrict__ off,
                                                const float* __restrict__ x,
                                                float* __restrict__ out,
                                                int wid, int lane) {
  int beg = off[wid], deg = off[wid + 1] - beg;
  float a0 = 0.f, a1 = 0.f, a2 = 0.f, a3 = 0.f;
  int j = 0;
  for (; j + 4 <= deg; j += 4) {
    int s0 = adj[beg + j], s1 = adj[beg + j + 1];
    int s2 = adj[beg + j + 2], s3 = adj[beg + j + 3];
    a0 += x[(size_t)s0 * CDIM + lane];
    a1 += x[(size_t)s1 * CDIM + lane];
    a2 += x[(size_t)s2 * CDIM + lane];
    a3 += x[(size_t)s3 * CDIM + lane];
  }
  for (; j < deg; ++j) a0 += x[(size_t)adj[beg + j] * CDIM + lane];
  float s = (a0 + a1) + (a2 + a3);
  out[(size_t)wid * CDIM + lane] = (deg > 0) ? s / (float)deg : 0.f;
}

__global__ __launch_bounds__(256) void agg_csr_k(const int* __restrict__ adj,
                                                 const int* __restrict__ off,
                                                 const float* __restrict__ x,
                                                 float* __restrict__ out, int N) {
  int wid = (blockIdx.x * 256 + threadIdx.x) >> 6;
  int lane = threadIdx.x & 63;
  if (wid >= N) return;
  csr_gather_body(adj, off, x, out, wid, lane);
}

// Fused multi-set CSR aggregation (all sets N=NS).
struct MAgg {
  const int* adj[4];
  const int* off[4];
  const float* x[4];
  float* out[4];
};
__global__ __launch_bounds__(256) void agg_multi_k(MAgg a) {
  int set = blockIdx.y;
  int wid = (blockIdx.x * 256 + threadIdx.x) >> 6;
  int lane = threadIdx.x & 63;
  if (wid >= NS) return;
  csr_gather_body(a.adj[set], a.off[set], a.x[set], a.out[set], wid, lane);
}

// ---------------------------------------------------------------------------
// Small-dst aggregation (genres=50, type=10): two-stage, no global atomics.
// ---------------------------------------------------------------------------
__global__ __launch_bounds__(256) void agg_small1(const int* __restrict__ src,
                                                  const int* __restrict__ dst, int E,
                                                  const float* __restrict__ x,
                                                  float* __restrict__ partial,
                                                  int* __restrict__ pcnt, int nd, int G) {
  __shared__ float acc[NG * CDIM];
  __shared__ int cnt[NG];
  int t = threadIdx.x, lane = t & 63, wv = t >> 6;
  for (int i = t; i < nd * CDIM; i += 256) acc[i] = 0.f;
  for (int i = t; i < nd; i += 256) cnt[i] = 0;
  __syncthreads();
  for (int j0 = (blockIdx.x * 4 + wv) * 64; j0 < E; j0 += G * 256) {
    int myj = j0 + lane;
    int s = 0, d = 0;
    if (myj < E) { s = src[myj]; d = dst[myj]; }
    int m = min(64, E - j0);
    int j = 0;
    for (; j + 4 <= m; j += 4) {
      int s0 = __shfl(s, j, 64), s1 = __shfl(s, j + 1, 64);
      int s2 = __shfl(s, j + 2, 64), s3 = __shfl(s, j + 3, 64);
      int d0 = __shfl(d, j, 64), d1 = __shfl(d, j + 1, 64);
      int d2 = __shfl(d, j + 2, 64), d3 = __shfl(d, j + 3, 64);
      float v0 = x[(size_t)s0 * CDIM + lane];
      float v1 = x[(size_t)s1 * CDIM + lane];
      float v2 = x[(size_t)s2 * CDIM + lane];
      float v3 = x[(size_t)s3 * CDIM + lane];
      atomicAdd(&acc[d0 * CDIM + lane], v0);
      atomicAdd(&acc[d1 * CDIM + lane], v1);
      atomicAdd(&acc[d2 * CDIM + lane], v2);
      atomicAdd(&acc[d3 * CDIM + lane], v3);
      if (lane == 0) {
        atomicAdd(&cnt[d0], 1); atomicAdd(&cnt[d1], 1);
        atomicAdd(&cnt[d2], 1); atomicAdd(&cnt[d3], 1);
      }
    }
    for (; j < m; ++j) {
      int sj = __shfl(s, j, 64), dj = __shfl(d, j, 64);
      atomicAdd(&acc[dj * CDIM + lane], x[(size_t)sj * CDIM + lane]);
      if (lane == 0) atomicAdd(&cnt[dj], 1);
    }
  }
  __syncthreads();
  float* po = partial + (size_t)blockIdx.x * nd * CDIM;
  for (int i = t; i < nd * CDIM; i += 256) po[i] = acc[i];
  int* pc = pcnt + blockIdx.x * nd;
  for (int i = t; i < nd; i += 256) pc[i] = cnt[i];
}

__global__ __launch_bounds__(256) void agg_small2(const float* __restrict__ partial,
                                                  const int* __restrict__ pcnt,
                                                  float* __restrict__ out, int nd, int G) {
  __shared__ float red[4][CDIM];
  __shared__ int redc[4];
  int d = blockIdx.x, t = threadIdx.x, c = t & 63, sl = t >> 6;
  float s = 0.f;
  int k = 0;
  for (int g = sl; g < G; g += 4) {
    s += partial[(size_t)g * nd * CDIM + d * CDIM + c];
    if (c == 0) k += pcnt[g * nd + d];
  }
  red[sl][c] = s;
  if (c == 0) redc[sl] = k;
  __syncthreads();
  if (sl == 0) {
    float tot = red[0][c] + red[1][c] + red[2][c] + red[3][c];
    int kt = redc[0] + redc[1] + redc[2] + redc[3];
    out[d * CDIM + c] = (kt > 0) ? tot / (float)kt : 0.f;
  }
}

// ---------------------------------------------------------------------------
// Weight prep: split weights into bf16 hi/lo planes, stored PRE-SWIZZLED in
// MFMA B-fragment order: within each 64xF plane, dst index
//   u = ((k0/32)*4 + nt)*512 + lane*8 + j
// holds element [row = nt*16 + (lane&15)][col = (k0/32)*32 + (lane>>4)*8 + j].
// A wave's B-fragment load is then one contiguous 1KB coalesced read.
// Region layout (ushort units) unchanged from R6. Total 376832 ushorts.
// ---------------------------------------------------------------------------
#define W_TOTAL 188416

__device__ __forceinline__ int swz_src(int u, int F) {
  int p = u >> 11;            // k-panel
  int nt = (u >> 9) & 3;      // n-tile
  int lane = (u >> 3) & 63;
  int j = u & 7;
  int row = nt * 16 + (lane & 15);
  int col = p * 32 + ((lane >> 4) << 3) + j;
  return row * F + col;
}

__global__ __launch_bounds__(256) void wprep_k(const float* __restrict__ Wu,
                                               const float* __restrict__ Wsp,
                                               const float* __restrict__ Wl1,
                                               const float* __restrict__ Wr1,
                                               const float* __restrict__ Wl2,
                                               const float* __restrict__ Wr2,
                                               ushort* __restrict__ S) {
  int i = blockIdx.x * 256 + threadIdx.x;
  if (i >= W_TOTAL) return;
  float v;
  size_t hbase, lbase;
  int u;
  if (i < 24576) {
    u = i; hbase = 0; lbase = 24576;
    v = Wu[swz_src(u, FDIM)];
  } else if (i < 49152) {
    u = i - 24576; hbase = 49152; lbase = 73728;
    v = Wsp[swz_src(u, FDIM)];
  } else {
    int j = i - 49152;
    int layer = j / 69632;
    j %= 69632;
    const float* Wl = layer ? Wl2 : Wl1;
    const float* Wr = layer ? Wr2 : Wr1;
    size_t base = 98304 + (size_t)layer * 139264;
    if (j < 32768) {
      int s = j >> 12; u = j & 4095;
      hbase = base + (size_t)s * 4096; lbase = base + 32768 + (size_t)s * 4096;
      v = Wl[s * 4096 + swz_src(u, 64)];
    } else if (j < 65536) {
      int q = j - 32768; int s = q >> 12; u = q & 4095;
      hbase = base + 65536 + (size_t)s * 4096; lbase = base + 98304 + (size_t)s * 4096;
      v = Wr[s * 4096 + swz_src(u, 64)];
    } else {
      u = j - 65536;
      hbase = base + 131072; lbase = base + 135168;
      int si = swz_src(u, 64);
      v = Wr[si] + Wr[8192 + si] + Wr[16384 + si] + Wr[24576 + si];
    }
  }
  uint b = __float_as_uint(v);
  uint h = b & 0xFFFF0000u;
  float r = v - __uint_as_float(h);
  S[hbase + u] = (ushort)(h >> 16);
  S[lbase + u] = (ushort)(__float_as_uint(r) >> 16);
}

// ---------------------------------------------------------------------------
// MFMA segmented GEMM (bf16 hi/lo split, 3-term: AhBh + AlBh + AhBl).
// W planes pre-swizzled to fragment order -> coalesced 1KB B-loads.
// 64(M)x64(N) per block, 4 waves (wave = 16 M-rows), 4 n-tiles/wave.
// ---------------------------------------------------------------------------
struct GSeg { const float* A; const ushort* Wh; const ushort* Wl; int F; };
struct GArgs {
  GSeg seg[5];
  const float* bias[4];
  float* out;
  int nseg, nbias, M, relu;
};

__device__ __forceinline__ void split8(const float* __restrict__ p, bf16x8& hi, bf16x8& lo) {
  float4 v0 = *(const float4*)p;
  float4 v1 = *(const float4*)(p + 4);
  float a[8] = {v0.x, v0.y, v0.z, v0.w, v1.x, v1.y, v1.z, v1.w};
  union { uint u[4]; bf16x8 v; } H, L;
#pragma unroll
  for (int i = 0; i < 4; ++i) {
    uint u0 = __float_as_uint(a[2 * i]), u1 = __float_as_uint(a[2 * i + 1]);
    uint h0 = u0 & 0xFFFF0000u, h1 = u1 & 0xFFFF0000u;
    float r0 = a[2 * i] - __uint_as_float(h0);
    float r1 = a[2 * i + 1] - __uint_as_float(h1);
    H.u[i] = (h0 >> 16) | h1;
    L.u[i] = ((__float_as_uint(r0) & 0xFFFF0000u) >> 16) | (__float_as_uint(r1) & 0xFFFF0000u);
  }
  hi = H.v;
  lo = L.v;
}

__global__ __launch_bounds__(256) void mfma_gemm(GArgs g) {
  const int tid = threadIdx.x;
  const int lane = tid & 63, wv = tid >> 6;
  const int ln = lane & 15, quad = lane >> 4;
  const int m0 = blockIdx.x * 64;
  f32x4 acc[4];
#pragma unroll
  for (int nt = 0; nt < 4; ++nt) acc[nt] = (f32x4){0.f, 0.f, 0.f, 0.f};

  const int ar = min(m0 + 16 * wv + ln, g.M - 1);  // A-frag row (clamped)

  for (int s = 0; s < g.nseg; ++s) {
    const float* __restrict__ A = g.seg[s].A;
    const ushort* __restrict__ whl = g.seg[s].Wh + (size_t)lane * 8;
    const ushort* __restrict__ wll = g.seg[s].Wl + (size_t)lane * 8;
    const int F = g.seg[s].F;
    const float* ap = A + (size_t)ar * F + quad * 8;
    for (int k0 = 0; k0 < F; k0 += 32) {
      bf16x8 ah, al;
      split8(ap + k0, ah, al);
      const size_t pb = (size_t)(k0 >> 5) * 2048;
#pragma unroll
      for (int nt = 0; nt < 4; ++nt) {
        bf16x8 bh = *(const bf16x8*)(whl + pb + nt * 512);
        bf16x8 bl = *(const bf16x8*)(wll + pb + nt * 512);
        acc[nt] = __builtin_amdgcn_mfma_f32_16x16x32_bf16(ah, bh, acc[nt], 0, 0, 0);
        acc[nt] = __builtin_amdgcn_mfma_f32_16x16x32_bf16(al, bh, acc[nt], 0, 0, 0);
        acc[nt] = __builtin_amdgcn_mfma_f32_16x16x32_bf16(ah, bl, acc[nt], 0, 0, 0);
      }
    }
  }

#pragma unroll
  for (int nt = 0; nt < 4; ++nt) {
    int c = nt * 16 + ln;
    float b = 0.f;
    for (int i = 0; i < g.nbias; ++i) b += g.bias[i][c];
#pragma unroll
    for (int r = 0; r < 4; ++r) {
      int m = m0 + 16 * wv + quad * 4 + r;
      if (m < g.M) {
        float o = acc[nt][r] + b;
        if (g.relu) o = fmaxf(o, 0.f);
        g.out[(size_t)m * CDIM + c] = o;
      }
    }
  }
}

// ---------------------------------------------------------------------------
// Edge scoring: one wave per edge, wave-reduce dot over 64 channels.
// ---------------------------------------------------------------------------
__global__ __launch_bounds__(256) void score_k(const int* __restrict__ eli, int E,
                                               const float* __restrict__ xu,
                                               const float* __restrict__ xs,
                                               float* __restrict__ out) {
  long long gid = (long long)blockIdx.x * 256 + threadIdx.x;
  int e = (int)(gid >> 6);
  int c = (int)(gid & 63);
  if (e < E) {
    int u = eli[e];
    int sv = eli[E + e];
    float p = xu[(size_t)u * CDIM + c] * xs[(size_t)sv * CDIM + c];
#pragma unroll
    for (int off = 32; off > 0; off >>= 1) p += __shfl_down(p, off, 64);
    if (c == 0) out[e] = p;
  }
}

extern "C" void kernel_launch(void* const* d_in, const int* in_sizes, int n_in,
                              void* d_out, int out_size, void* d_ws, size_t ws_size,
                              hipStream_t stream) {
  const float* reviews  = (const float*)d_in[0];
  const float* overview = (const float*)d_in[1];
  const float* g_emb    = (const float*)d_in[2];
  const float* w_emb    = (const float*)d_in[3];
  const float* t_emb    = (const float*)d_in[4];
  const float* Wu  = (const float*)d_in[5];
  const float* bu  = (const float*)d_in[6];
  const float* Wsp = (const float*)d_in[7];
  const float* bs  = (const float*)d_in[8];
  const float* Wl1 = (const float*)d_in[9];
  const float* bl1 = (const float*)d_in[10];
  const float* Wr1 = (const float*)d_in[11];
  const float* Wl2 = (const float*)d_in[12];
  const float* bl2 = (const float*)d_in[13];
  const float* Wr2 = (const float*)d_in[14];
  const int* e_u2s = (const int*)d_in[15];
  const int* e_g2s = (const int*)d_in[16];
  const int* e_w2s = (const int*)d_in[17];
  const int* e_t2s = (const int*)d_in[18];
  const int* eli   = (const int*)d_in[19];
  const int E_u = in_sizes[15] / 2;
  const int E_g = in_sizes[16] / 2;
  const int E_w = in_sizes[17] / 2;
  const int E_t = in_sizes[18] / 2;
  const int E_l = in_sizes[19] / 2;

  // ---- workspace layout (4B units) ----
  float* ws = (float*)d_ws;
  size_t off = 0;
  auto take = [&](size_t n) { float* p = ws + off; off += n; return p; };
  float* x0u = take((size_t)NU * CDIM);
  float* x0s = take((size_t)NS * CDIM);
  float* x1u = take((size_t)NU * CDIM);
  float* x1s = take((size_t)NS * CDIM);
  float* x1g = take((size_t)NG * CDIM);
  float* x1w = take((size_t)NW * CDIM);
  float* x1t = take((size_t)NT * CDIM);
  float* aggS0 = take((size_t)NS * CDIM);
  float* aggS2 = take((size_t)NS * CDIM);
  float* aggS4 = take((size_t)NS * CDIM);
  float* aggS6 = take((size_t)NS * CDIM);
  float* agg1  = aggS0;  // NU*CDIM alias over aggS0+aggS2 (disjoint lifetime)
  float* agg5  = take((size_t)NW * CDIM);
  float* agg3  = take((size_t)NG * CDIM);
  float* agg7  = take((size_t)NT * CDIM);
  // small-agg partials (shared genres/type, sequential use)
  float* spart = take((size_t)256 * NG * CDIM);
  int* spcnt   = (int*)take((size_t)256 * NG);
  // split weights: 2*W_TOTAL ushorts = W_TOTAL floats
  ushort* wsplit = (ushort*)take((size_t)W_TOTAL);
  // buckets + CSR (types 0,1,2,4,5,6)
  int* bkt0 = (int*)take(E_u);
  int* bkt1 = (int*)take(E_u);
  int* bkt2 = (int*)take(E_g);
  int* bkt3 = (int*)take(E_w);
  int* bkt4 = (int*)take(E_w);
  int* bkt5 = (int*)take(E_t);
  int* adj0 = (int*)take(E_u);
  int* adj1 = (int*)take(E_u);
  int* adj2 = (int*)take(E_g);
  int* adj3 = (int*)take(E_w);
  int* adj4 = (int*)take(E_w);
  int* adj5 = (int*)take(E_t);
  int* off0 = (int*)take(NS + 1);
  int* off1 = (int*)take(NU + 1);
  int* off2 = (int*)take(NS + 1);
  int* off3 = (int*)take(NS + 1);
  int* off4 = (int*)take(NW + 1);
  int* off5 = (int*)take(NS + 1);
  int* partial  = (int*)take((size_t)BTOT * PSTRIDE);
  int* chunktot = (int*)take(NBINS);
  int* choffG   = (int*)take(NBINS + 6);
  float* x2u = x0u;
  float* x2s = x0s;

  // split-weight offsets (ushort units)
  const ushort* WuH = wsplit + 0;
  const ushort* WuL = wsplit + 24576;
  const ushort* WsH = wsplit + 49152;
  const ushort* WsL = wsplit + 73728;
  auto WlH = [&](int layer, int seg) { return wsplit + 98304 + (size_t)layer * 139264 + (size_t)seg * 4096; };
  auto WlL = [&](int layer, int seg) { return wsplit + 98304 + (size_t)layer * 139264 + 32768 + (size_t)seg * 4096; };
  auto WrH = [&](int layer, int seg) { return wsplit + 98304 + (size_t)layer * 139264 + 65536 + (size_t)seg * 4096; };
  auto WrL = [&](int layer, int seg) { return wsplit + 98304 + (size_t)layer * 139264 + 98304 + (size_t)seg * 4096; };
  auto WrsH = [&](int layer) { return wsplit + 98304 + (size_t)layer * 139264 + 131072; };
  auto WrsL = [&](int layer) { return wsplit + 98304 + (size_t)layer * 139264 + 135168; };

  // ---- prep args ----
  PrepArgs pa{};
  const int* bsrc[6] = {e_u2s, e_u2s + E_u, e_g2s, e_w2s, e_w2s + E_w, e_t2s};
  const int* bdst[6] = {e_u2s + E_u, e_u2s, e_g2s + E_g, e_w2s + E_w, e_w2s, e_t2s + E_t};
  int bE[6]  = {E_u, E_u, E_g, E_w, E_w, E_t};
  int nch[6] = {391, 782, 391, 391, 157, 391};
  int cb[7]  = {0, 391, 1173, 1564, 1955, 2112, 2503};
  int bpt[6] = {128, 128, 32, 16, 16, 32};
  int nbT[6] = {NS, NU, NS, NS, NW, NS};
  int* bkts[6] = {bkt0, bkt1, bkt2, bkt3, bkt4, bkt5};
  int* adjs[6] = {adj0, adj1, adj2, adj3, adj4, adj5};
  int* offs[6] = {off0, off1, off2, off3, off4, off5};
  int bb = 0, cs = 0;
  for (int i = 0; i < 6; ++i) {
    pa.src[i] = bsrc[i]; pa.dst[i] = bdst[i]; pa.E[i] = bE[i];
    pa.nchunk[i] = nch[i]; pa.nb[i] = nbT[i]; pa.cbase[i] = cb[i];
    pa.bbase[i] = bb; bb += bpt[i];
    pa.cstart[i] = cs; cs += nch[i];
    pa.bucket[i] = bkts[i]; pa.adj[i] = adjs[i]; pa.off[i] = offs[i];
  }
  pa.cbase[6] = cb[6]; pa.bbase[6] = bb; pa.cstart[6] = cs;
  pa.partial = partial; pa.chunktot = chunktot; pa.choff = choffG;

  // ---- prep + weight split ----
  wprep_k<<<(W_TOTAL + 255) / 256, 256, 0, stream>>>(Wu, Wsp, Wl1, Wr1, Wl2, Wr2, wsplit);
  hist_k<<<BTOT, 256, 0, stream>>>(pa);
  scanb_k<<<(NBINS + 255) / 256, 256, 0, stream>>>(pa);
  scanc_k<<<6, 1024, 0, stream>>>(pa);
  fill_k<<<BTOT, 256, 0, stream>>>(pa);
  csr_k<<<CTOT, 256, 0, stream>>>(pa);

  // embedding-driven series aggs (3 sets fused)
  {
    MAgg a{};
    a.adj[0] = adj2; a.off[0] = off2; a.x[0] = g_emb; a.out[0] = aggS2;
    a.adj[1] = adj3; a.off[1] = off3; a.x[1] = w_emb; a.out[1] = aggS4;
    a.adj[2] = adj5; a.off[2] = off5; a.x[2] = t_emb; a.out[2] = aggS6;
    dim3 grid((NS * 64 + 255) / 256, 3);
    agg_multi_k<<<grid, 256, 0, stream>>>(a);
  }

  // ---- projections ----
  {
    GArgs a{};
    a.seg[0] = {reviews, WuH, WuL, FDIM}; a.nseg = 1;
    a.bias[0] = bu; a.nbias = 1;
    a.out = x0u; a.M = NU; a.relu = 0;
    mfma_gemm<<<(NU + 63) / 64, 256, 0, stream>>>(a);
  }
  {
    GArgs a{};
    a.seg[0] = {overview, WsH, WsL, FDIM}; a.nseg = 1;
    a.bias[0] = bs; a.nbias = 1;
    a.out = x0s; a.M = NS; a.relu = 0;
    mfma_gemm<<<(NS + 63) / 64, 256, 0, stream>>>(a);
  }

  // ---- layer 1 ----
  agg_csr_k<<<(NS * 64 + 255) / 256, 256, 0, stream>>>(adj0, off0, x0u, aggS0, NS);
  {  // series (4 Wl segs + x0s * sum(Wr))
    GArgs a{};
    a.seg[0] = {aggS0, WlH(0, 0), WlL(0, 0), 64};
    a.seg[1] = {aggS2, WlH(0, 2), WlL(0, 2), 64};
    a.seg[2] = {aggS4, WlH(0, 4), WlL(0, 4), 64};
    a.seg[3] = {aggS6, WlH(0, 6), WlL(0, 6), 64};
    a.seg[4] = {x0s, WrsH(0), WrsL(0), 64};
    a.nseg = 5;
    a.bias[0] = bl1 + 0 * 64; a.bias[1] = bl1 + 2 * 64;
    a.bias[2] = bl1 + 4 * 64; a.bias[3] = bl1 + 6 * 64; a.nbias = 4;
    a.out = x1s; a.M = NS; a.relu = 1;
    mfma_gemm<<<(NS + 63) / 64, 256, 0, stream>>>(a);
  }
  agg_csr_k<<<(NU * 64 + 255) / 256, 256, 0, stream>>>(adj1, off1, x0s, agg1, NU);
  {  // users
    GArgs a{};
    a.seg[0] = {agg1, WlH(0, 1), WlL(0, 1), 64};
    a.seg[1] = {x0u, WrH(0, 1), WrL(0, 1), 64};
    a.nseg = 2;
    a.bias[0] = bl1 + 1 * 64; a.nbias = 1;
    a.out = x1u; a.M = NU; a.relu = 1;
    mfma_gemm<<<(NU + 63) / 64, 256, 0, stream>>>(a);
  }
  // genres (two-stage small)
  agg_small1<<<256, 256, 0, stream>>>(e_g2s + E_g, e_g2s, E_g, x0s, spart, spcnt, NG, 256);
  agg_small2<<<NG, 256, 0, stream>>>(spart, spcnt, agg3, NG, 256);
  {
    GArgs a{};
    a.seg[0] = {agg3, WlH(0, 3), WlL(0, 3), 64};
    a.seg[1] = {g_emb, WrH(0, 3), WrL(0, 3), 64};
    a.nseg = 2;
    a.bias[0] = bl1 + 3 * 64; a.nbias = 1;
    a.out = x1g; a.M = NG; a.relu = 1;
    mfma_gemm<<<1, 256, 0, stream>>>(a);
  }
  // writer (CSR)
  agg_csr_k<<<(NW * 64 + 255) / 256, 256, 0, stream>>>(adj4, off4, x0s, agg5, NW);
  {
    GArgs a{};
    a.seg[0] = {agg5, WlH(0, 5), WlL(0, 5), 64};
    a.seg[1] = {w_emb, WrH(0, 5), WrL(0, 5), 64};
    a.nseg = 2;
    a.bias[0] = bl1 + 5 * 64; a.nbias = 1;
    a.out = x1w; a.M = NW; a.relu = 1;
    mfma_gemm<<<(NW + 63) / 64, 256, 0, stream>>>(a);
  }
  // type (two-stage small)
  agg_small1<<<128, 256, 0, stream>>>(e_t2s + E_t, e_t2s, E_t, x0s, spart, spcnt, NT, 128);
  agg_small2<<<NT, 256, 0, stream>>>(spart, spcnt, agg7, NT, 128);
  {
    GArgs a{};
    a.seg[0] = {agg7, WlH(0, 7), WlL(0, 7), 64};
    a.seg[1] = {t_emb, WrH(0, 7), WrL(0, 7), 64};
    a.nseg = 2;
    a.bias[0] = bl1 + 7 * 64; a.nbias = 1;
    a.out = x1t; a.M = NT; a.relu = 1;
    mfma_gemm<<<1, 256, 0, stream>>>(a);
  }

  // ---- layer 2 ----
  {  // 4 series aggs fused
    MAgg a{};
    a.adj[0] = adj0; a.off[0] = off0; a.x[0] = x1u; a.out[0] = aggS0;
    a.adj[1] = adj2; a.off[1] = off2; a.x[1] = x1g; a.out[1] = aggS2;
    a.adj[2] = adj3; a.off[2] = off3; a.x[2] = x1w; a.out[2] = aggS4;
    a.adj[3] = adj5; a.off[3] = off5; a.x[3] = x1t; a.out[3] = aggS6;
    dim3 grid((NS * 64 + 255) / 256, 4);
    agg_multi_k<<<grid, 256, 0, stream>>>(a);
  }
  {  // series -> x2s
    GArgs a{};
    a.seg[0] = {aggS0, WlH(1, 0), WlL(1, 0), 64};
    a.seg[1] = {aggS2, WlH(1, 2), WlL(1, 2), 64};
    a.seg[2] = {aggS4, WlH(1, 4), WlL(1, 4), 64};
    a.seg[3] = {aggS6, WlH(1, 6), WlL(1, 6), 64};
    a.seg[4] = {x1s, WrsH(1), WrsL(1), 64};
    a.nseg = 5;
    a.bias[0] = bl2 + 0 * 64; a.bias[1] = bl2 + 2 * 64;
    a.bias[2] = bl2 + 4 * 64; a.bias[3] = bl2 + 6 * 64; a.nbias = 4;
    a.out = x2s; a.M = NS; a.relu = 0;
    mfma_gemm<<<(NS + 63) / 64, 256, 0, stream>>>(a);
  }
  agg_csr_k<<<(NU * 64 + 255) / 256, 256, 0, stream>>>(adj1, off1, x1s, agg1, NU);
  {  // users -> x2u
    GArgs a{};
    a.seg[0] = {agg1, WlH(1, 1), WlL(1, 1), 64};
    a.seg[1] = {x1u, WrH(1, 1), WrL(1, 1), 64};
    a.nseg = 2;
    a.bias[0] = bl2 + 1 * 64; a.nbias = 1;
    a.out = x2u; a.M = NU; a.relu = 0;
    mfma_gemm<<<(NU + 63) / 64, 256, 0, stream>>>(a);
  }

  // ---- scoring ----
  score_k<<<((long long)E_l * 64 + 255) / 256, 256, 0, stream>>>(
      eli, E_l, x2u, x2s, (float*)d_out);
}

// Round 8
// 893.808 us; speedup vs baseline: 3.6342x; 1.1976x over previous
//
#include <hip/hip_runtime.h>

#define NU 100000
#define NS 50000
#define NG 50
#define NW 20000
#define NT 10
#define CDIM 64
#define FDIM 384

typedef short bf16x8 __attribute__((ext_vector_type(8)));
typedef float f32x4 __attribute__((ext_vector_type(4)));
typedef unsigned short ushort;
typedef unsigned int uint;

#define CHUNK 128
#define CSHIFT 7
#define CMASK 127
#define NBINS 2503      // 391+782+391+391+157+391
#define PSTRIDE 800
#define BTOT 352
#define CTOT 2503
#define W_TOTAL 188416
#define WPB 736         // wprep blocks

struct PrepArgs {
  const int* src[6];
  const int* dst[6];
  int E[6];
  int nchunk[6];
  int nb[6];
  int cbase[7];
  int bbase[7];
  int cstart[7];
  int* partial;   // [BTOT][PSTRIDE]
  int* chunktot;  // [NBINS]
  int* choff;     // [NBINS + 6]
  int* bucket[6];
  int* adj[6];
  int* off[6];
};

struct WArgs {
  const float* Wu; const float* Wsp;
  const float* Wl1; const float* Wr1;
  const float* Wl2; const float* Wr2;
  ushort* S;
};

// ---------------- prep bodies ----------------
__device__ __forceinline__ void hist_body(const PrepArgs& a, int b, int t, int* bins) {
  int ty = 0;
  while (b >= a.bbase[ty + 1]) ++ty;
  int bl = b - a.bbase[ty], B = a.bbase[ty + 1] - a.bbase[ty];
  int n = a.nchunk[ty], E = a.E[ty];
  const int* __restrict__ dst = a.dst[ty];
  for (int i = t; i < n; i += 256) bins[i] = 0;
  __syncthreads();
  for (int i = bl * 256 + t; i < E; i += B * 256) atomicAdd(&bins[dst[i] >> CSHIFT], 1);
  __syncthreads();
  int* row = a.partial + (size_t)b * PSTRIDE;
  for (int i = t; i < n; i += 256) row[i] = bins[i];
}

__device__ __forceinline__ void scanb_body(const PrepArgs& a, int bin) {
  if (bin >= NBINS) return;
  int ty = 0;
  while (bin >= a.cbase[ty + 1]) ++ty;
  int l = bin - a.cbase[ty];
  int run = 0;
  for (int b = a.bbase[ty]; b < a.bbase[ty + 1]; ++b) {
    int* p = a.partial + (size_t)b * PSTRIDE + l;
    int v = *p;
    *p = run;
    run += v;
  }
  a.chunktot[bin] = run;
}

__device__ __forceinline__ void scanc_body(const PrepArgs& a, int ty, int t, int* sc) {
  int n = a.nchunk[ty];
  int chunk = (n + 255) / 256;
  int lo = t * chunk, hi = min(n, lo + chunk);
  const int* __restrict__ cnt = a.chunktot + a.cbase[ty];
  int s = 0;
  for (int i = lo; i < hi; ++i) s += cnt[i];
  sc[t] = s;
  __syncthreads();
  for (int d = 1; d < 256; d <<= 1) {
    int u = (t >= d) ? sc[t - d] : 0;
    __syncthreads();
    sc[t] += u;
    __syncthreads();
  }
  int* choff = a.choff + a.cbase[ty] + ty;
  int carry = (t > 0) ? sc[t - 1] : 0;
  for (int i = lo; i < hi; ++i) { choff[i] = carry; carry += cnt[i]; }
  if (t == 255) choff[n] = sc[255];
}

__device__ __forceinline__ void fill_body(const PrepArgs& a, int b, int t, int* bins, int* base) {
  int ty = 0;
  while (b >= a.bbase[ty + 1]) ++ty;
  int bl = b - a.bbase[ty], B = a.bbase[ty + 1] - a.bbase[ty];
  int n = a.nchunk[ty], E = a.E[ty];
  const int* __restrict__ dst = a.dst[ty];
  const int* __restrict__ src = a.src[ty];
  int* __restrict__ bucket = a.bucket[ty];
  const int* choff = a.choff + a.cbase[ty] + ty;
  const int* prow = a.partial + (size_t)b * PSTRIDE;
  for (int i = t; i < n; i += 256) { bins[i] = 0; base[i] = choff[i] + prow[i]; }
  __syncthreads();
  for (int i = bl * 256 + t; i < E; i += B * 256) {
    int d = dst[i];
    int l = d >> CSHIFT;
    int r = atomicAdd(&bins[l], 1);
    bucket[base[l] + r] = (src[i] << CSHIFT) | (d & CMASK);
  }
}

__device__ __forceinline__ void csr_body(const PrepArgs& a, int b, int t,
                                         int* bins, int* sc, int* basea) {
  int ty = 0;
  while (b >= a.cstart[ty + 1]) ++ty;
  int c = b - a.cstart[ty];
  const int* __restrict__ bucket = a.bucket[ty];
  const int* choff = a.choff + a.cbase[ty] + ty;
  int beg = choff[c], end = choff[c + 1];
  if (t < CHUNK) bins[t] = 0;
  __syncthreads();
  for (int i = beg + t; i < end; i += 256) atomicAdd(&bins[bucket[i] & CMASK], 1);
  __syncthreads();
  int v = (t < CHUNK) ? bins[t] : 0;
  if (t < CHUNK) sc[t] = v;
  __syncthreads();
#pragma unroll
  for (int d = 1; d < CHUNK; d <<= 1) {
    int u = (t < CHUNK && t >= d) ? sc[t - d] : 0;
    __syncthreads();
    if (t < CHUNK) sc[t] += u;
    __syncthreads();
  }
  if (t < CHUNK) { basea[t] = beg + sc[t] - v; bins[t] = basea[t]; }
  __syncthreads();
  int gbase = c * CHUNK;
  int nb = a.nb[ty];
  if (t < CHUNK && gbase + t < nb) a.off[ty][gbase + t] = basea[t];
  if (b == a.cstart[ty + 1] - 1 && t == 0) a.off[ty][nb] = choff[a.nchunk[ty]];
  int* __restrict__ adj = a.adj[ty];
  for (int i = beg + t; i < end; i += 256) {
    int pk = bucket[i];
    int r = atomicAdd(&bins[pk & CMASK], 1);
    adj[r] = pk >> CSHIFT;
  }
}

// ---------------- weight split (pre-swizzled to MFMA B-fragment order) ------
__device__ __forceinline__ int swz_src(int u, int F) {
  int p = u >> 11;
  int nt = (u >> 9) & 3;
  int lane = (u >> 3) & 63;
  int j = u & 7;
  int row = nt * 16 + (lane & 15);
  int col = p * 32 + ((lane >> 4) << 3) + j;
  return row * F + col;
}

__device__ __forceinline__ void wprep_body(const WArgs& w, int i) {
  if (i >= W_TOTAL) return;
  float v;
  size_t hbase, lbase;
  int u;
  if (i < 24576) {
    u = i; hbase = 0; lbase = 24576;
    v = w.Wu[swz_src(u, FDIM)];
  } else if (i < 49152) {
    u = i - 24576; hbase = 49152; lbase = 73728;
    v = w.Wsp[swz_src(u, FDIM)];
  } else {
    int j = i - 49152;
    int layer = j / 69632;
    j %= 69632;
    const float* Wl = layer ? w.Wl2 : w.Wl1;
    const float* Wr = layer ? w.Wr2 : w.Wr1;
    size_t base = 98304 + (size_t)layer * 139264;
    if (j < 32768) {
      int s = j >> 12; u = j & 4095;
      hbase = base + (size_t)s * 4096; lbase = base + 32768 + (size_t)s * 4096;
      v = Wl[s * 4096 + swz_src(u, 64)];
    } else if (j < 65536) {
      int q = j - 32768; int s = q >> 12; u = q & 4095;
      hbase = base + 65536 + (size_t)s * 4096; lbase = base + 98304 + (size_t)s * 4096;
      v = Wr[s * 4096 + swz_src(u, 64)];
    } else {
      u = j - 65536;
      hbase = base + 131072; lbase = base + 135168;
      int si = swz_src(u, 64);
      v = Wr[si] + Wr[8192 + si] + Wr[16384 + si] + Wr[24576 + si];
    }
  }
  uint b = __float_as_uint(v);
  uint h = b & 0xFFFF0000u;
  float r = v - __uint_as_float(h);
  w.S[hbase + u] = (ushort)(h >> 16);
  w.S[lbase + u] = (ushort)(__float_as_uint(r) >> 16);
}

// ---------------- CSR gather ----------------
__device__ __forceinline__ void csr_gather_body(const int* __restrict__ adj,
                                                const int* __restrict__ off,
                                                const float* __restrict__ x,
                                                float* __restrict__ out,
                                                int wid, int lane) {
  int beg = off[wid], deg = off[wid + 1] - beg;
  float a0 = 0.f, a1 = 0.f, a2 = 0.f, a3 = 0.f;
  int j = 0;
  for (; j + 4 <= deg; j += 4) {
    int s0 = adj[beg + j], s1 = adj[beg + j + 1];
    int s2 = adj[beg + j + 2], s3 = adj[beg + j + 3];
    a0 += x[(size_t)s0 * CDIM + lane];
    a1 += x[(size_t)s1 * CDIM + lane];
    a2 += x[(size_t)s2 * CDIM + lane];
    a3 += x[(size_t)s3 * CDIM + lane];
  }
  for (; j < deg; ++j) a0 += x[(size_t)adj[beg + j] * CDIM + lane];
  float s = (a0 + a1) + (a2 + a3);
  out[(size_t)wid * CDIM + lane] = (deg > 0) ? s / (float)deg : 0.f;
}

struct AggArgs {
  const int* adj[6];
  const int* off[6];
  const float* x[6];
  float* out[6];
  int N[6];
  int start[7];
  int ntask;
};

__global__ __launch_bounds__(256) void agg_fused(AggArgs a) {
  int b = blockIdx.x;
  int ti = 0;
  while (b >= a.start[ti + 1]) ++ti;
  int wid = (b - a.start[ti]) * 4 + (threadIdx.x >> 6);
  int lane = threadIdx.x & 63;
  if (wid >= a.N[ti]) return;
  csr_gather_body(a.adj[ti], a.off[ti], a.x[ti], a.out[ti], wid, lane);
}

// ---------------- small-dst agg (two-stage) ----------------
struct SmallT { const int* src; const int* dst; int E; const float* x;
                float* partial; int* pcnt; int nd; int G; };
struct Small2T { const float* partial; const int* pcnt; float* out; int nd; int G; };

__device__ __forceinline__ void small1_body(const SmallT& s, int blk, int t, int* smem) {
  float* acc = (float*)smem;
  int* cnt = smem + s.nd * CDIM;
  int lane = t & 63, wv = t >> 6;
  for (int i = t; i < s.nd * CDIM; i += 256) acc[i] = 0.f;
  for (int i = t; i < s.nd; i += 256) cnt[i] = 0;
  __syncthreads();
  const int* __restrict__ src = s.src;
  const int* __restrict__ dst = s.dst;
  const float* __restrict__ x = s.x;
  int E = s.E;
  for (int j0 = (blk * 4 + wv) * 64; j0 < E; j0 += s.G * 256) {
    int myj = j0 + lane;
    int sv = 0, dv = 0;
    if (myj < E) { sv = src[myj]; dv = dst[myj]; }
    int m = min(64, E - j0);
    int j = 0;
    for (; j + 4 <= m; j += 4) {
      int s0 = __shfl(sv, j, 64), s1 = __shfl(sv, j + 1, 64);
      int s2 = __shfl(sv, j + 2, 64), s3 = __shfl(sv, j + 3, 64);
      int d0 = __shfl(dv, j, 64), d1 = __shfl(dv, j + 1, 64);
      int d2 = __shfl(dv, j + 2, 64), d3 = __shfl(dv, j + 3, 64);
      float v0 = x[(size_t)s0 * CDIM + lane];
      float v1 = x[(size_t)s1 * CDIM + lane];
      float v2 = x[(size_t)s2 * CDIM + lane];
      float v3 = x[(size_t)s3 * CDIM + lane];
      atomicAdd(&acc[d0 * CDIM + lane], v0);
      atomicAdd(&acc[d1 * CDIM + lane], v1);
      atomicAdd(&acc[d2 * CDIM + lane], v2);
      atomicAdd(&acc[d3 * CDIM + lane], v3);
      if (lane == 0) {
        atomicAdd(&cnt[d0], 1); atomicAdd(&cnt[d1], 1);
        atomicAdd(&cnt[d2], 1); atomicAdd(&cnt[d3], 1);
      }
    }
    for (; j < m; ++j) {
      int sj = __shfl(sv, j, 64), dj = __shfl(dv, j, 64);
      atomicAdd(&acc[dj * CDIM + lane], x[(size_t)sj * CDIM + lane]);
      if (lane == 0) atomicAdd(&cnt[dj], 1);
    }
  }
  __syncthreads();
  float* po = s.partial + (size_t)blk * s.nd * CDIM;
  for (int i = t; i < s.nd * CDIM; i += 256) po[i] = acc[i];
  int* pc = s.pcnt + blk * s.nd;
  for (int i = t; i < s.nd; i += 256) pc[i] = cnt[i];
}

__device__ __forceinline__ void small2_body(const Small2T& s, int d, int t, int* smem) {
  float* red = (float*)smem;          // [4][64]
  int* redc = smem + 256;             // [4]
  int c = t & 63, sl = t >> 6;
  float sum = 0.f;
  int k = 0;
  for (int g = sl; g < s.G; g += 4) {
    sum += s.partial[(size_t)g * s.nd * CDIM + d * CDIM + c];
    if (c == 0) k += s.pcnt[g * s.nd + d];
  }
  red[sl * 64 + c] = sum;
  if (c == 0) redc[sl] = k;
  __syncthreads();
  if (sl == 0) {
    float tot = red[c] + red[64 + c] + red[128 + c] + red[192 + c];
    int kt = redc[0] + redc[1] + redc[2] + redc[3];
    s.out[d * CDIM + c] = (kt > 0) ? tot / (float)kt : 0.f;
  }
}

// ---------------- MFMA GEMM (bf16 hi/lo, pre-swizzled W) ----------------
struct GSeg { const float* A; const ushort* Wh; const ushort* Wl; int F; };
struct GArgs {
  GSeg seg[5];
  const float* bias[4];
  float* out;
  int nseg, nbias, M, relu;
};
struct GemmMulti { GArgs g[5]; int start[6]; int n; };

__device__ __forceinline__ void split8(const float* __restrict__ p, bf16x8& hi, bf16x8& lo) {
  float4 v0 = *(const float4*)p;
  float4 v1 = *(const float4*)(p + 4);
  float a[8] = {v0.x, v0.y, v0.z, v0.w, v1.x, v1.y, v1.z, v1.w};
  union { uint u[4]; bf16x8 v; } H, L;
#pragma unroll
  for (int i = 0; i < 4; ++i) {
    uint u0 = __float_as_uint(a[2 * i]), u1 = __float_as_uint(a[2 * i + 1]);
    uint h0 = u0 & 0xFFFF0000u, h1 = u1 & 0xFFFF0000u;
    float r0 = a[2 * i] - __uint_as_float(h0);
    float r1 = a[2 * i + 1] - __uint_as_float(h1);
    H.u[i] = (h0 >> 16) | h1;
    L.u[i] = ((__float_as_uint(r0) & 0xFFFF0000u) >> 16) | (__float_as_uint(r1) & 0xFFFF0000u);
  }
  hi = H.v;
  lo = L.v;
}

__device__ __forceinline__ void mfma_body(const GArgs& g, int mb, int tid) {
  const int lane = tid & 63, wv = tid >> 6;
  const int ln = lane & 15, quad = lane >> 4;
  const int m0 = mb * 64;
  f32x4 acc[4];
#pragma unroll
  for (int nt = 0; nt < 4; ++nt) acc[nt] = (f32x4){0.f, 0.f, 0.f, 0.f};

  const int ar = min(m0 + 16 * wv + ln, g.M - 1);

  for (int s = 0; s < g.nseg; ++s) {
    const float* __restrict__ A = g.seg[s].A;
    const ushort* __restrict__ whl = g.seg[s].Wh + (size_t)lane * 8;
    const ushort* __restrict__ wll = g.seg[s].Wl + (size_t)lane * 8;
    const int F = g.seg[s].F;
    const float* ap = A + (size_t)ar * F + quad * 8;
    for (int k0 = 0; k0 < F; k0 += 32) {
      bf16x8 ah, al;
      split8(ap + k0, ah, al);
      const size_t pb = (size_t)(k0 >> 5) * 2048;
#pragma unroll
      for (int nt = 0; nt < 4; ++nt) {
        bf16x8 bh = *(const bf16x8*)(whl + pb + nt * 512);
        bf16x8 bl = *(const bf16x8*)(wll + pb + nt * 512);
        acc[nt] = __builtin_amdgcn_mfma_f32_16x16x32_bf16(ah, bh, acc[nt], 0, 0, 0);
        acc[nt] = __builtin_amdgcn_mfma_f32_16x16x32_bf16(al, bh, acc[nt], 0, 0, 0);
        acc[nt] = __builtin_amdgcn_mfma_f32_16x16x32_bf16(ah, bl, acc[nt], 0, 0, 0);
      }
    }
  }

#pragma unroll
  for (int nt = 0; nt < 4; ++nt) {
    int c = nt * 16 + ln;
    float b = 0.f;
    for (int i = 0; i < g.nbias; ++i) b += g.bias[i][c];
#pragma unroll
    for (int r = 0; r < 4; ++r) {
      int m = m0 + 16 * wv + quad * 4 + r;
      if (m < g.M) {
        float o = acc[nt][r] + b;
        if (g.relu) o = fmaxf(o, 0.f);
        g.out[(size_t)m * CDIM + c] = o;
      }
    }
  }
}

__global__ __launch_bounds__(256) void gemm_multi_k(GemmMulti gm) {
  int b = blockIdx.x;
  int i = 0;
  while (b >= gm.start[i + 1]) ++i;
  mfma_body(gm.g[i], b - gm.start[i], threadIdx.x);
}

// ---------------- fused stage kernels ----------------
__global__ __launch_bounds__(256) void s1_k(PrepArgs pa, WArgs wa) {
  __shared__ int smem[PSTRIDE];
  int b = blockIdx.x;
  if (b < BTOT) hist_body(pa, b, threadIdx.x, smem);
  else wprep_body(wa, (b - BTOT) * 256 + threadIdx.x);
}

__global__ __launch_bounds__(256) void s2_k(PrepArgs pa, GArgs g) {
  int b = blockIdx.x;
  if (b < 10) scanb_body(pa, b * 256 + threadIdx.x);
  else mfma_body(g, b - 10, threadIdx.x);
}

__global__ __launch_bounds__(256) void s3_k(PrepArgs pa, GArgs g) {
  __shared__ int smem[256];
  int b = blockIdx.x;
  if (b < 6) scanc_body(pa, b, threadIdx.x, smem);
  else mfma_body(g, b - 6, threadIdx.x);
}

__global__ __launch_bounds__(256) void s4_k(PrepArgs pa, SmallT sg, SmallT st) {
  __shared__ int smem[3264];
  int b = blockIdx.x;
  if (b < BTOT) fill_body(pa, b, threadIdx.x, smem, smem + PSTRIDE);
  else if (b < BTOT + 256) small1_body(sg, b - BTOT, threadIdx.x, smem);
  else small1_body(st, b - BTOT - 256, threadIdx.x, smem);
}

__global__ __launch_bounds__(256) void s5_k(PrepArgs pa, Small2T g2, Small2T t2) {
  __shared__ int smem[384];
  int b = blockIdx.x;
  if (b < CTOT) csr_body(pa, b, threadIdx.x, smem, smem + CHUNK, smem + 2 * CHUNK);
  else if (b < CTOT + NG) small2_body(g2, b - CTOT, threadIdx.x, smem);
  else small2_body(t2, b - CTOT - NG, threadIdx.x, smem);
}

// ---------------- scoring ----------------
__global__ __launch_bounds__(256) void score_k(const int* __restrict__ eli, int E,
                                               const float* __restrict__ xu,
                                               const float* __restrict__ xs,
                                               float* __restrict__ out) {
  long long gid = (long long)blockIdx.x * 256 + threadIdx.x;
  int e = (int)(gid >> 6);
  int c = (int)(gid & 63);
  if (e < E) {
    int u = eli[e];
    int sv = eli[E + e];
    float p = xu[(size_t)u * CDIM + c] * xs[(size_t)sv * CDIM + c];
#pragma unroll
    for (int off = 32; off > 0; off >>= 1) p += __shfl_down(p, off, 64);
    if (c == 0) out[e] = p;
  }
}

extern "C" void kernel_launch(void* const* d_in, const int* in_sizes, int n_in,
                              void* d_out, int out_size, void* d_ws, size_t ws_size,
                              hipStream_t stream) {
  const float* reviews  = (const float*)d_in[0];
  const float* overview = (const float*)d_in[1];
  const float* g_emb    = (const float*)d_in[2];
  const float* w_emb    = (const float*)d_in[3];
  const float* t_emb    = (const float*)d_in[4];
  const float* Wu  = (const float*)d_in[5];
  const float* bu  = (const float*)d_in[6];
  const float* Wsp = (const float*)d_in[7];
  const float* bs  = (const float*)d_in[8];
  const float* Wl1 = (const float*)d_in[9];
  const float* bl1 = (const float*)d_in[10];
  const float* Wr1 = (const float*)d_in[11];
  const float* Wl2 = (const float*)d_in[12];
  const float* bl2 = (const float*)d_in[13];
  const float* Wr2 = (const float*)d_in[14];
  const int* e_u2s = (const int*)d_in[15];
  const int* e_g2s = (const int*)d_in[16];
  const int* e_w2s = (const int*)d_in[17];
  const int* e_t2s = (const int*)d_in[18];
  const int* eli   = (const int*)d_in[19];
  const int E_u = in_sizes[15] / 2;
  const int E_g = in_sizes[16] / 2;
  const int E_w = in_sizes[17] / 2;
  const int E_t = in_sizes[18] / 2;
  const int E_l = in_sizes[19] / 2;

  // ---- workspace (ws_size ~614MB; we use ~190MB) ----
  float* ws = (float*)d_ws;
  size_t off = 0;
  auto take = [&](size_t n) { float* p = ws + off; off += n; return p; };
  float* x0u = take((size_t)NU * CDIM);
  float* x0s = take((size_t)NS * CDIM);
  float* x1u = take((size_t)NU * CDIM);
  float* x1s = take((size_t)NS * CDIM);
  float* x1g = take((size_t)NG * CDIM);
  float* x1w = take((size_t)NW * CDIM);
  float* x1t = take((size_t)NT * CDIM);
  float* aggS0 = take((size_t)NS * CDIM);
  float* aggS2 = take((size_t)NS * CDIM);
  float* aggS4 = take((size_t)NS * CDIM);
  float* aggS6 = take((size_t)NS * CDIM);
  float* agg1  = take((size_t)NU * CDIM);   // standalone (concurrent with aggS*)
  float* agg5  = take((size_t)NW * CDIM);
  float* agg3  = take((size_t)NG * CDIM);
  float* agg7  = take((size_t)NT * CDIM);
  float* spartG = take((size_t)256 * NG * CDIM);
  int* spcntG   = (int*)take((size_t)256 * NG);
  float* spartT = take((size_t)128 * NT * CDIM);
  int* spcntT   = (int*)take((size_t)128 * NT);
  ushort* wsplit = (ushort*)take((size_t)W_TOTAL);  // 2*W_TOTAL ushorts
  int* bkt0 = (int*)take(E_u);
  int* bkt1 = (int*)take(E_u);
  int* bkt2 = (int*)take(E_g);
  int* bkt3 = (int*)take(E_w);
  int* bkt4 = (int*)take(E_w);
  int* bkt5 = (int*)take(E_t);
  int* adj0 = (int*)take(E_u);
  int* adj1 = (int*)take(E_u);
  int* adj2 = (int*)take(E_g);
  int* adj3 = (int*)take(E_w);
  int* adj4 = (int*)take(E_w);
  int* adj5 = (int*)take(E_t);
  int* off0 = (int*)take(NS + 1);
  int* off1 = (int*)take(NU + 1);
  int* off2 = (int*)take(NS + 1);
  int* off3 = (int*)take(NS + 1);
  int* off4 = (int*)take(NW + 1);
  int* off5 = (int*)take(NS + 1);
  int* partial  = (int*)take((size_t)BTOT * PSTRIDE);
  int* chunktot = (int*)take(NBINS);
  int* choffG   = (int*)take(NBINS + 6);
  float* x2u = x0u;
  float* x2s = x0s;

  // split-weight region offsets (ushort units)
  const ushort* WuH = wsplit + 0;
  const ushort* WuL = wsplit + 24576;
  const ushort* WsH = wsplit + 49152;
  const ushort* WsL = wsplit + 73728;
  auto WlH = [&](int layer, int seg) { return wsplit + 98304 + (size_t)layer * 139264 + (size_t)seg * 4096; };
  auto WlL = [&](int layer, int seg) { return wsplit + 98304 + (size_t)layer * 139264 + 32768 + (size_t)seg * 4096; };
  auto WrH = [&](int layer, int seg) { return wsplit + 98304 + (size_t)layer * 139264 + 65536 + (size_t)seg * 4096; };
  auto WrL = [&](int layer, int seg) { return wsplit + 98304 + (size_t)layer * 139264 + 98304 + (size_t)seg * 4096; };
  auto WrsH = [&](int layer) { return wsplit + 98304 + (size_t)layer * 139264 + 131072; };
  auto WrsL = [&](int layer) { return wsplit + 98304 + (size_t)layer * 139264 + 135168; };

  // ---- prep args ----
  PrepArgs pa{};
  const int* bsrc[6] = {e_u2s, e_u2s + E_u, e_g2s, e_w2s, e_w2s + E_w, e_t2s};
  const int* bdst[6] = {e_u2s + E_u, e_u2s, e_g2s + E_g, e_w2s + E_w, e_w2s, e_t2s + E_t};
  int bE[6]  = {E_u, E_u, E_g, E_w, E_w, E_t};
  int nch[6] = {391, 782, 391, 391, 157, 391};
  int cb[7]  = {0, 391, 1173, 1564, 1955, 2112, 2503};
  int bpt[6] = {128, 128, 32, 16, 16, 32};
  int nbT[6] = {NS, NU, NS, NS, NW, NS};
  int* bkts[6] = {bkt0, bkt1, bkt2, bkt3, bkt4, bkt5};
  int* adjs[6] = {adj0, adj1, adj2, adj3, adj4, adj5};
  int* offs[6] = {off0, off1, off2, off3, off4, off5};
  int bb = 0, cs = 0;
  for (int i = 0; i < 6; ++i) {
    pa.src[i] = bsrc[i]; pa.dst[i] = bdst[i]; pa.E[i] = bE[i];
    pa.nchunk[i] = nch[i]; pa.nb[i] = nbT[i]; pa.cbase[i] = cb[i];
    pa.bbase[i] = bb; bb += bpt[i];
    pa.cstart[i] = cs; cs += nch[i];
    pa.bucket[i] = bkts[i]; pa.adj[i] = adjs[i]; pa.off[i] = offs[i];
  }
  pa.cbase[6] = cb[6]; pa.bbase[6] = bb; pa.cstart[6] = cs;
  pa.partial = partial; pa.chunktot = chunktot; pa.choff = choffG;

  WArgs wa{Wu, Wsp, Wl1, Wr1, Wl2, Wr2, wsplit};

  // ---- S1: hist + weight split ----
  s1_k<<<BTOT + WPB, 256, 0, stream>>>(pa, wa);

  // ---- S2: scanb + NU projection ----
  {
    GArgs g{};
    g.seg[0] = {reviews, WuH, WuL, FDIM}; g.nseg = 1;
    g.bias[0] = bu; g.nbias = 1;
    g.out = x0u; g.M = NU; g.relu = 0;
    s2_k<<<10 + (NU + 63) / 64, 256, 0, stream>>>(pa, g);
  }
  // ---- S3: scanc + NS projection ----
  {
    GArgs g{};
    g.seg[0] = {overview, WsH, WsL, FDIM}; g.nseg = 1;
    g.bias[0] = bs; g.nbias = 1;
    g.out = x0s; g.M = NS; g.relu = 0;
    s3_k<<<6 + (NS + 63) / 64, 256, 0, stream>>>(pa, g);
  }
  // ---- S4: fill + small1(genres) + small1(type) ----
  {
    SmallT sg{e_g2s, e_g2s + E_g, E_g, x0s, spartG, spcntG, NG, 256};
    SmallT st{e_t2s, e_t2s + E_t, E_t, x0s, spartT, spcntT, NT, 128};
    // note: src for genres agg is series side? edge type 3 is series->genres:
    // src = e_g2s[1] (series ids), dst = e_g2s[0] (genre ids)
    sg.src = e_g2s + E_g; sg.dst = e_g2s;
    st.src = e_t2s + E_t; st.dst = e_t2s;
    s4_k<<<BTOT + 256 + 128, 256, 0, stream>>>(pa, sg, st);
  }
  // ---- S5: csr + small2(genres) + small2(type) ----
  {
    Small2T g2{spartG, spcntG, agg3, NG, 256};
    Small2T t2{spartT, spcntT, agg7, NT, 128};
    s5_k<<<CTOT + NG + NT, 256, 0, stream>>>(pa, g2, t2);
  }
  // ---- S6: layer-1 gathers (series/users/writer + 3 embedding sets) ----
  {
    AggArgs a{};
    const int* aadj[6] = {adj0, adj1, adj4, adj2, adj3, adj5};
    const int* aoff[6] = {off0, off1, off4, off2, off3, off5};
    const float* ax[6] = {x0u, x0s, x0s, g_emb, w_emb, t_emb};
    float* aout[6] = {aggS0, agg1, agg5, aggS2, aggS4, aggS6};
    int aN[6] = {NS, NU, NW, NS, NS, NS};
    int s = 0;
    for (int i = 0; i < 6; ++i) {
      a.adj[i] = aadj[i]; a.off[i] = aoff[i]; a.x[i] = ax[i];
      a.out[i] = aout[i]; a.N[i] = aN[i];
      a.start[i] = s; s += (aN[i] + 3) / 4;
    }
    a.start[6] = s; a.ntask = 6;
    agg_fused<<<s, 256, 0, stream>>>(a);
  }
  // ---- S7: all layer-1 GEMMs ----
  {
    GemmMulti gm{};
    // series
    gm.g[0].seg[0] = {aggS0, WlH(0, 0), WlL(0, 0), 64};
    gm.g[0].seg[1] = {aggS2, WlH(0, 2), WlL(0, 2), 64};
    gm.g[0].seg[2] = {aggS4, WlH(0, 4), WlL(0, 4), 64};
    gm.g[0].seg[3] = {aggS6, WlH(0, 6), WlL(0, 6), 64};
    gm.g[0].seg[4] = {x0s, WrsH(0), WrsL(0), 64};
    gm.g[0].nseg = 5;
    gm.g[0].bias[0] = bl1 + 0 * 64; gm.g[0].bias[1] = bl1 + 2 * 64;
    gm.g[0].bias[2] = bl1 + 4 * 64; gm.g[0].bias[3] = bl1 + 6 * 64; gm.g[0].nbias = 4;
    gm.g[0].out = x1s; gm.g[0].M = NS; gm.g[0].relu = 1;
    // users
    gm.g[1].seg[0] = {agg1, WlH(0, 1), WlL(0, 1), 64};
    gm.g[1].seg[1] = {x0u, WrH(0, 1), WrL(0, 1), 64};
    gm.g[1].nseg = 2;
    gm.g[1].bias[0] = bl1 + 1 * 64; gm.g[1].nbias = 1;
    gm.g[1].out = x1u; gm.g[1].M = NU; gm.g[1].relu = 1;
    // writer
    gm.g[2].seg[0] = {agg5, WlH(0, 5), WlL(0, 5), 64};
    gm.g[2].seg[1] = {w_emb, WrH(0, 5), WrL(0, 5), 64};
    gm.g[2].nseg = 2;
    gm.g[2].bias[0] = bl1 + 5 * 64; gm.g[2].nbias = 1;
    gm.g[2].out = x1w; gm.g[2].M = NW; gm.g[2].relu = 1;
    // genres
    gm.g[3].seg[0] = {agg3, WlH(0, 3), WlL(0, 3), 64};
    gm.g[3].seg[1] = {g_emb, WrH(0, 3), WrL(0, 3), 64};
    gm.g[3].nseg = 2;
    gm.g[3].bias[0] = bl1 + 3 * 64; gm.g[3].nbias = 1;
    gm.g[3].out = x1g; gm.g[3].M = NG; gm.g[3].relu = 1;
    // type
    gm.g[4].seg[0] = {agg7, WlH(0, 7), WlL(0, 7), 64};
    gm.g[4].seg[1] = {t_emb, WrH(0, 7), WrL(0, 7), 64};
    gm.g[4].nseg = 2;
    gm.g[4].bias[0] = bl1 + 7 * 64; gm.g[4].nbias = 1;
    gm.g[4].out = x1t; gm.g[4].M = NT; gm.g[4].relu = 1;
    int mb[5] = {(NS + 63) / 64, (NU + 63) / 64, (NW + 63) / 64, 1, 1};
    int s = 0;
    for (int i = 0; i < 5; ++i) { gm.start[i] = s; s += mb[i]; }
    gm.start[5] = s; gm.n = 5;
    gemm_multi_k<<<s, 256, 0, stream>>>(gm);
  }
  // ---- S8: layer-2 gathers ----
  {
    AggArgs a{};
    const int* aadj[5] = {adj0, adj2, adj3, adj5, adj1};
    const int* aoff[5] = {off0, off2, off3, off5, off1};
    const float* ax[5] = {x1u, x1g, x1w, x1t, x1s};
    float* aout[5] = {aggS0, aggS2, aggS4, aggS6, agg1};
    int aN[5] = {NS, NS, NS, NS, NU};
    int s = 0;
    for (int i = 0; i < 5; ++i) {
      a.adj[i] = aadj[i]; a.off[i] = aoff[i]; a.x[i] = ax[i];
      a.out[i] = aout[i]; a.N[i] = aN[i];
      a.start[i] = s; s += (aN[i] + 3) / 4;
    }
    a.start[5] = s; a.start[6] = s; a.ntask = 5;
    agg_fused<<<s, 256, 0, stream>>>(a);
  }
  // ---- S9: layer-2 GEMMs ----
  {
    GemmMulti gm{};
    gm.g[0].seg[0] = {aggS0, WlH(1, 0), WlL(1, 0), 64};
    gm.g[0].seg[1] = {aggS2, WlH(1, 2), WlL(1, 2), 64};
    gm.g[0].seg[2] = {aggS4, WlH(1, 4), WlL(1, 4), 64};
    gm.g[0].seg[3] = {aggS6, WlH(1, 6), WlL(1, 6), 64};
    gm.g[0].seg[4] = {x1s, WrsH(1), WrsL(1), 64};
    gm.g[0].nseg = 5;
    gm.g[0].bias[0] = bl2 + 0 * 64; gm.g[0].bias[1] = bl2 + 2 * 64;
    gm.g[0].bias[2] = bl2 + 4 * 64; gm.g[0].bias[3] = bl2 + 6 * 64; gm.g[0].nbias = 4;
    gm.g[0].out = x2s; gm.g[0].M = NS; gm.g[0].relu = 0;
    gm.g[1].seg[0] = {agg1, WlH(1, 1), WlL(1, 1), 64};
    gm.g[1].seg[1] = {x1u, WrH(1, 1), WrL(1, 1), 64};
    gm.g[1].nseg = 2;
    gm.g[1].bias[0] = bl2 + 1 * 64; gm.g[1].nbias = 1;
    gm.g[1].out = x2u; gm.g[1].M = NU; gm.g[1].relu = 0;
    int s = 0;
    gm.start[0] = 0; s += (NS + 63) / 64;
    gm.start[1] = s; s += (NU + 63) / 64;
    gm.start[2] = s; gm.start[3] = s; gm.start[4] = s; gm.start[5] = s;
    gm.n = 2;
    gemm_multi_k<<<s, 256, 0, stream>>>(gm);
  }
  // ---- S10: scoring ----
  score_k<<<((long long)E_l * 64 + 255) / 256, 256, 0, stream>>>(
      eli, E_l, x2u, x2s, (float*)d_out);
}